// Round 4
// baseline (424.184 us; speedup 1.0000x reference)
//
#include <hip/hip_runtime.h>
#include <hip/hip_bf16.h>

// AttnBlock: GroupNorm + single-head attention (N=1024 tokens, C=512) + residual.
// B=16. All GEMMs on MFMA via SPLIT-BF16 (hi+lo bf16 pair per fp32 value;
// C = Ah*Bh + Ah*Bl + Al*Bh, lo*lo dropped ~2^-16) -> fp32-class accuracy at
// bf16 MFMA rate. No fp32 MFMA exists on CDNA4.
//
// Pipeline:
//  1. gn_stats : per-(b,group) mean/rstd -> per-(b,c) affine (fp32)
//  2. prep_h   : x NCHW -> h = affine(x), transposed to [b][n][c], split hi/lo
//  3. prep_w   : wq, wk -> split hi/lo bf16 [oc][ic]
//  4. weff     : Weff = wp @ wv (fp32 VALU, 0.27 GF) -> split hi/lo
//  5. bsum     : bsum[p] = bp[p] + sum_o wp[p][o]*bv[o]  (valid since softmax
//                rows sum to 1: attn@(vp+beff) = attn@vp + beff)
//  6. gemm_qkv : q = (h wq^T + bq)*C^-0.5, k = h wk^T + bk (split, [b][n][c]);
//                vp^T = (h Weff^T)^T (split, [b][p][n])   -- v never materialized
//  7. gemm_scores: per-batch q k^T -> scores fp32 [b][n][m]
//  8. softmax  : row softmax, in-place rewrite as split-bf16 planes (hi|lo per row)
//  9. gemm_out : attn @ vp^T^T; epilogue + bsum + residual x -> NCHW fp32 out
//
// Split-GEMM core: 128x128 tile, BK=32, 4 waves x (4x4 frags 16x16x32), 48 MFMA
// per wave per K-step. LDS rows 128 B (hi/lo interleaved per 32 B), XOR-swizzled
// (byte ^= (row&7)<<4) on both ds_write and ds_read -> ~2-way conflicts.
// Double-buffered (64 KB LDS = 2 blocks/CU), global loads issued before MFMA.
// NOTE: LDS accessed by indexing the __shared__ array directly at each use —
// storing (char*)lds in a braced pointer-array initializer is a compile error
// on gfx950 (constant addrspacecast). Workspace ~196 MB.

#define B_ 16
#define C_ 512
#define NTOK_ 1024
#define CPG_ 16
#define EPS_ 1e-5f
#define QSCALE_ 0.04419417382415922f  // 512^-0.5

typedef __attribute__((ext_vector_type(8))) short short8;  // 8 bf16 = 4 VGPR
typedef __attribute__((ext_vector_type(4))) float f32x4;

// ---- bf16 split helpers (RNE) ----
__device__ __forceinline__ ushort bf16_rne(float x) {
    union { float f; unsigned u; } v; v.f = x;
    unsigned r = v.u + 0x7fffu + ((v.u >> 16) & 1u);
    return (ushort)(r >> 16);
}
__device__ __forceinline__ float bf2f(ushort h) {
    union { unsigned u; float f; } v; v.u = (unsigned)h << 16; return v.f;
}
__device__ __forceinline__ void split2(float x, ushort& hi, ushort& lo) {
    hi = bf16_rne(x);
    lo = bf16_rne(x - bf2f(hi));
}

// =================== split-bf16 MFMA GEMM core ===================
// C[M=128 rows of A][N=128 rows of Bt] += A · Bt^T, both operands row-major
// along K (lda/ldb in ushort elements), hi/lo planes. K multiple of 32.
// acc[m][n]: wave (wm,wn) owns rows wm*64+m*16+4*lk+reg, cols wn*64+n*16+lrow.
__device__ __forceinline__ void gemm_core_split(
    const ushort* __restrict__ Ah, const ushort* __restrict__ Al, int lda,
    const ushort* __restrict__ Bh, const ushort* __restrict__ Bl, int ldb,
    int K, f32x4 acc[4][4])
{
    // [buf][A=0|B=1][16 KB tile] = 64 KB total
    __shared__ alignas(16) char ldsc[2][2][16384];

    const int tid  = threadIdx.x;
    const int wave = tid >> 6, lane = tid & 63;
    const int wm = wave >> 1, wn = wave & 1;
    const int lrow = lane & 15, lk = lane >> 4;
    const int r  = tid >> 2;      // staging row 0..63 (and +64)
    const int ch = tid & 3;       // k-chunk (8 elems)

    // LDS write byte offsets: row*128 + swizzle(chunk*32 [+16 for lo])
    const int sw  = (r & 7) << 4;
    const int wb0h = r * 128        + ((ch * 32)      ^ sw);
    const int wb0l = r * 128        + ((ch * 32 + 16) ^ sw);
    const int wb1h = (r + 64) * 128 + ((ch * 32)      ^ sw);  // (r+64)&7 == r&7
    const int wb1l = (r + 64) * 128 + ((ch * 32 + 16) ^ sw);

    const ushort* pAh = Ah + (size_t)r * lda + ch * 8;
    const ushort* pAl = Al + (size_t)r * lda + ch * 8;
    const ushort* pBh = Bh + (size_t)r * ldb + ch * 8;
    const ushort* pBl = Bl + (size_t)r * ldb + ch * 8;
    const size_t a64 = (size_t)64 * lda, b64 = (size_t)64 * ldb;

    uint4 va0, va1, va2, va3, vb0, vb1, vb2, vb3;

#define LOADSTEP(k0) do { \
    va0 = *(const uint4*)(pAh + (k0));       va1 = *(const uint4*)(pAl + (k0)); \
    va2 = *(const uint4*)(pAh + a64 + (k0)); va3 = *(const uint4*)(pAl + a64 + (k0)); \
    vb0 = *(const uint4*)(pBh + (k0));       vb1 = *(const uint4*)(pBl + (k0)); \
    vb2 = *(const uint4*)(pBh + b64 + (k0)); vb3 = *(const uint4*)(pBl + b64 + (k0)); \
} while (0)

#define WRITESTEP(buf) do { \
    char* _la = &ldsc[buf][0][0]; char* _lb = &ldsc[buf][1][0]; \
    *(uint4*)(_la + wb0h) = va0; *(uint4*)(_la + wb0l) = va1; \
    *(uint4*)(_la + wb1h) = va2; *(uint4*)(_la + wb1l) = va3; \
    *(uint4*)(_lb + wb0h) = vb0; *(uint4*)(_lb + wb0l) = vb1; \
    *(uint4*)(_lb + wb1h) = vb2; *(uint4*)(_lb + wb1l) = vb3; \
} while (0)

    LOADSTEP(0);
    WRITESTEP(0);
    __syncthreads();

    const int nsteps = K >> 5;
    for (int t = 0; t < nsteps; ++t) {
        const int cur = t & 1;
        if (t + 1 < nsteps) LOADSTEP((t + 1) << 5);

        short8 afh[4], afl[4], bfh[4], bfl[4];
#pragma unroll
        for (int m = 0; m < 4; ++m) {
            int row = wm * 64 + m * 16 + lrow;
            const char* base = &ldsc[cur][0][0] + row * 128;
            int s = (row & 7) << 4;
            afh[m] = *(const short8*)(base + ((lk * 32)      ^ s));
            afl[m] = *(const short8*)(base + ((lk * 32 + 16) ^ s));
        }
#pragma unroll
        for (int n = 0; n < 4; ++n) {
            int row = wn * 64 + n * 16 + lrow;
            const char* base = &ldsc[cur][1][0] + row * 128;
            int s = (row & 7) << 4;
            bfh[n] = *(const short8*)(base + ((lk * 32)      ^ s));
            bfl[n] = *(const short8*)(base + ((lk * 32 + 16) ^ s));
        }
#pragma unroll
        for (int m = 0; m < 4; ++m)
#pragma unroll
            for (int n = 0; n < 4; ++n) {
                acc[m][n] = __builtin_amdgcn_mfma_f32_16x16x32_bf16(afh[m], bfh[n], acc[m][n], 0, 0, 0);
                acc[m][n] = __builtin_amdgcn_mfma_f32_16x16x32_bf16(afh[m], bfl[n], acc[m][n], 0, 0, 0);
                acc[m][n] = __builtin_amdgcn_mfma_f32_16x16x32_bf16(afl[m], bfh[n], acc[m][n], 0, 0, 0);
            }
        if (t + 1 < nsteps) WRITESTEP((t + 1) & 1);
        __syncthreads();
    }
#undef LOADSTEP
#undef WRITESTEP
}

#define ACC_ZERO(acc) do { \
    _Pragma("unroll") for (int m_ = 0; m_ < 4; ++m_) \
    _Pragma("unroll") for (int n_ = 0; n_ < 4; ++n_) \
        acc[m_][n_] = (f32x4){0.f, 0.f, 0.f, 0.f}; \
} while (0)

// ---------------- 1. GroupNorm stats ----------------
__global__ __launch_bounds__(256) void gn_stats_kernel(
    const float* __restrict__ x, const float* __restrict__ gw,
    const float* __restrict__ gb, float* __restrict__ scale_a,
    float* __restrict__ bias_a) {
    int bg = blockIdx.x;
    int b = bg >> 5, g = bg & 31;
    const float4* xp = (const float4*)(x + (size_t)(b * C_ + g * CPG_) * NTOK_);
    int tid = threadIdx.x;
    float s = 0.f, ss = 0.f;
    for (int i = tid; i < 4096; i += 256) {
        float4 v = xp[i];
        s += v.x + v.y + v.z + v.w;
        ss += v.x * v.x + v.y * v.y + v.z * v.z + v.w * v.w;
    }
    __shared__ float red[8];
    __shared__ float smu, srstd;
#pragma unroll
    for (int off = 32; off; off >>= 1) {
        s += __shfl_down(s, off);
        ss += __shfl_down(ss, off);
    }
    int wid = tid >> 6, lane = tid & 63;
    if (lane == 0) { red[wid] = s; red[wid + 4] = ss; }
    __syncthreads();
    if (tid == 0) {
        float S = red[0] + red[1] + red[2] + red[3];
        float SS = red[4] + red[5] + red[6] + red[7];
        float mu = S * (1.f / 16384.f);
        float var = SS * (1.f / 16384.f) - mu * mu;
        smu = mu;
        srstd = rsqrtf(var + EPS_);
    }
    __syncthreads();
    if (tid < CPG_) {
        int c = g * CPG_ + tid;
        float sc = srstd * gw[c];
        scale_a[b * C_ + c] = sc;
        bias_a[b * C_ + c] = gb[c] - smu * sc;
    }
}

// ---------------- 2. prep_h: affine + transpose + split ----------------
// x[b][c][n] -> h_hi/h_lo [b][n][c].  Tile 64c x 64n per block.
__global__ __launch_bounds__(256) void prep_h_kernel(
    const float* __restrict__ x, const float* __restrict__ scale_a,
    const float* __restrict__ bias_a, ushort* __restrict__ h_hi,
    ushort* __restrict__ h_lo) {
    __shared__ ushort sh[64][72], sl[64][72];
    int tid = threadIdx.x;
    int ct = blockIdx.x, nt = blockIdx.y, b = blockIdx.z;
    int cl = tid >> 2, nq = tid & 3;
    int c = ct * 64 + cl;
    const float* xp = x + (((size_t)b * C_ + c) << 10) + nt * 64;
    float sc = scale_a[b * C_ + c], bi = bias_a[b * C_ + c];
#pragma unroll
    for (int i = 0; i < 4; ++i) {
        f32x4 v = *(const f32x4*)&xp[nq * 16 + i * 4];
#pragma unroll
        for (int j = 0; j < 4; ++j) {
            ushort h, l;
            split2(v[j] * sc + bi, h, l);
            sh[cl][nq * 16 + i * 4 + j] = h;
            sl[cl][nq * 16 + i * 4 + j] = l;
        }
    }
    __syncthreads();
    int nl = tid >> 2, cq = tid & 3;
    size_t ob = (((size_t)b << 10) + nt * 64 + nl) * C_ + ct * 64 + cq * 16;
    union { ushort u[8]; uint4 v; } p0, p1;
#pragma unroll
    for (int j = 0; j < 8; ++j) { p0.u[j] = sh[cq * 16 + j][nl]; p1.u[j] = sh[cq * 16 + 8 + j][nl]; }
    *(uint4*)&h_hi[ob] = p0.v;  *(uint4*)&h_hi[ob + 8] = p1.v;
#pragma unroll
    for (int j = 0; j < 8; ++j) { p0.u[j] = sl[cq * 16 + j][nl]; p1.u[j] = sl[cq * 16 + 8 + j][nl]; }
    *(uint4*)&h_lo[ob] = p0.v;  *(uint4*)&h_lo[ob + 8] = p1.v;
}

// ---------------- 3. prep_w: split wq, wk ----------------
__global__ __launch_bounds__(256) void prep_w_kernel(
    const float* __restrict__ wq, const float* __restrict__ wk,
    ushort* __restrict__ wqh, ushort* __restrict__ wql,
    ushort* __restrict__ wkh, ushort* __restrict__ wkl) {
    int i = blockIdx.x * 256 + threadIdx.x;  // one float4 of each matrix
    union { ushort u[4]; ushort4 v; } h, l;
    f32x4 a = ((const f32x4*)wq)[i];
#pragma unroll
    for (int j = 0; j < 4; ++j) split2(a[j], h.u[j], l.u[j]);
    ((ushort4*)wqh)[i] = h.v;  ((ushort4*)wql)[i] = l.v;
    f32x4 b = ((const f32x4*)wk)[i];
#pragma unroll
    for (int j = 0; j < 4; ++j) split2(b[j], h.u[j], l.u[j]);
    ((ushort4*)wkh)[i] = h.v;  ((ushort4*)wkl)[i] = l.v;
}

// ---------------- 4. Weff = wp @ wv (fp32, 64x64 tiles) -> split ----------------
__global__ __launch_bounds__(256) void weff_kernel(
    const float* __restrict__ wp, const float* __restrict__ wv,
    ushort* __restrict__ weh, ushort* __restrict__ wel) {
    __shared__ float As[16][68], Bs[16][68];
    int tid = threadIdx.x, ty = tid >> 4, tx = tid & 15;
    int c0 = blockIdx.x << 6, p0 = blockIdx.y << 6;
    int a_row = tid >> 2, a_kq = tid & 3;
    int b_m = tid >> 4, b_cq = tid & 15;
    float acc[4][4] = {};
    for (int k0 = 0; k0 < C_; k0 += 16) {
        f32x4 a4 = *(const f32x4*)&wp[(size_t)(p0 + a_row) * C_ + k0 + a_kq * 4];
        As[a_kq * 4 + 0][a_row] = a4[0]; As[a_kq * 4 + 1][a_row] = a4[1];
        As[a_kq * 4 + 2][a_row] = a4[2]; As[a_kq * 4 + 3][a_row] = a4[3];
        *(f32x4*)&Bs[b_m][b_cq * 4] =
            *(const f32x4*)&wv[(size_t)(k0 + b_m) * C_ + c0 + b_cq * 4];
        __syncthreads();
#pragma unroll
        for (int kk = 0; kk < 16; ++kk) {
            f32x4 av = *(const f32x4*)&As[kk][ty << 2];
            f32x4 bv = *(const f32x4*)&Bs[kk][tx << 2];
#pragma unroll
            for (int i = 0; i < 4; ++i)
#pragma unroll
                for (int j = 0; j < 4; ++j) acc[i][j] += av[i] * bv[j];
        }
        __syncthreads();
    }
#pragma unroll
    for (int i = 0; i < 4; ++i) {
        union { ushort u[4]; ushort4 v; } hh, ll;
#pragma unroll
        for (int j = 0; j < 4; ++j) split2(acc[i][j], hh.u[j], ll.u[j]);
        size_t o = (size_t)(p0 + ty * 4 + i) * C_ + c0 + tx * 4;
        *(ushort4*)&weh[o] = hh.v;  *(ushort4*)&wel[o] = ll.v;
    }
}

// ---------------- 5. bsum[p] = bp[p] + sum_o wp[p][o]*bv[o] ----------------
__global__ __launch_bounds__(256) void bsum_kernel(
    const float* __restrict__ wp, const float* __restrict__ bv,
    const float* __restrict__ bp, float* __restrict__ bsum) {
    int p = blockIdx.x * 256 + threadIdx.x;
    const float* row = wp + (size_t)p * C_;
    float s = bp[p];
    for (int o = 0; o < C_; o += 4) {
        f32x4 w = *(const f32x4*)&row[o];
        f32x4 b = *(const f32x4*)&bv[o];
        s += w[0] * b[0] + w[1] * b[1] + w[2] * b[2] + w[3] * b[3];
    }
    bsum[p] = s;
}

// ---------------- 6. qkv GEMM (q, k, vp^T from h) ----------------
__global__ __launch_bounds__(256) void gemm_qkv(
    const ushort* __restrict__ h_hi, const ushort* __restrict__ h_lo,
    const ushort* __restrict__ wqh, const ushort* __restrict__ wql,
    const ushort* __restrict__ wkh, const ushort* __restrict__ wkl,
    const ushort* __restrict__ weh, const ushort* __restrict__ wel,
    const float* __restrict__ bq, const float* __restrict__ bk,
    ushort* __restrict__ q_hi, ushort* __restrict__ q_lo,
    ushort* __restrict__ k_hi, ushort* __restrict__ k_lo,
    ushort* __restrict__ vpt_hi, ushort* __restrict__ vpt_lo) {
    int wsel = blockIdx.x >> 2, ct = blockIdx.x & 3;
    int mt = blockIdx.y;
    const ushort *Bh, *Bl;
    const float* bias = nullptr;
    if (wsel == 0)      { Bh = wqh; Bl = wql; bias = bq; }
    else if (wsel == 1) { Bh = wkh; Bl = wkl; bias = bk; }
    else                { Bh = weh; Bl = wel; }

    f32x4 acc[4][4]; ACC_ZERO(acc);
    gemm_core_split(h_hi + (size_t)mt * 128 * C_, h_lo + (size_t)mt * 128 * C_, C_,
                    Bh + (size_t)ct * 128 * C_,   Bl + (size_t)ct * 128 * C_,   C_,
                    C_, acc);

    int tid = threadIdx.x, wave = tid >> 6, lane = tid & 63;
    int wm = wave >> 1, wn = wave & 1, lrow = lane & 15, lk = lane >> 4;

    if (wsel < 2) {
        ushort* oh = wsel ? k_hi : q_hi;
        ushort* ol = wsel ? k_lo : q_lo;
        float scale = wsel ? 1.f : QSCALE_;
#pragma unroll
        for (int mf = 0; mf < 4; ++mf) {
            int gm = mt * 128 + wm * 64 + mf * 16 + 4 * lk;
#pragma unroll
            for (int nf = 0; nf < 4; ++nf) {
                int gc = ct * 128 + wn * 64 + nf * 16 + lrow;
                float bi = bias[gc];
#pragma unroll
                for (int rg = 0; rg < 4; ++rg) {
                    ushort h, l;
                    split2((acc[mf][nf][rg] + bi) * scale, h, l);
                    size_t o = (size_t)(gm + rg) * C_ + gc;
                    oh[o] = h; ol[o] = l;
                }
            }
        }
    } else {
        // vp^T [b][p][n]: 4 consecutive token-rows per reg-quad -> 8B stores
#pragma unroll
        for (int mf = 0; mf < 4; ++mf) {
            int gm0 = mt * 128 + wm * 64 + mf * 16 + 4 * lk;
            int b = gm0 >> 10, nl = gm0 & 1023;
#pragma unroll
            for (int nf = 0; nf < 4; ++nf) {
                int p = ct * 128 + wn * 64 + nf * 16 + lrow;
                union { ushort u[4]; ushort4 v; } hv, lv;
#pragma unroll
                for (int rg = 0; rg < 4; ++rg) split2(acc[mf][nf][rg], hv.u[rg], lv.u[rg]);
                size_t o = ((size_t)b * C_ + p) * NTOK_ + nl;
                *(ushort4*)&vpt_hi[o] = hv.v;
                *(ushort4*)&vpt_lo[o] = lv.v;
            }
        }
    }
}

// ---------------- 7. scores = q @ k^T (per batch), fp32 out ----------------
__global__ __launch_bounds__(256) void gemm_scores(
    const ushort* __restrict__ q_hi, const ushort* __restrict__ q_lo,
    const ushort* __restrict__ k_hi, const ushort* __restrict__ k_lo,
    float* __restrict__ s) {
    int nx = blockIdx.x, my = blockIdx.y, b = blockIdx.z;
    size_t ao = ((size_t)b * NTOK_ + my * 128) * C_;
    size_t bo = ((size_t)b * NTOK_ + nx * 128) * C_;
    f32x4 acc[4][4]; ACC_ZERO(acc);
    gemm_core_split(q_hi + ao, q_lo + ao, C_, k_hi + bo, k_lo + bo, C_, C_, acc);

    int tid = threadIdx.x, wave = tid >> 6, lane = tid & 63;
    int wm = wave >> 1, wn = wave & 1, lrow = lane & 15, lk = lane >> 4;
#pragma unroll
    for (int mf = 0; mf < 4; ++mf) {
        int n = my * 128 + wm * 64 + mf * 16 + 4 * lk;
#pragma unroll
        for (int nf = 0; nf < 4; ++nf) {
            int m = nx * 128 + wn * 64 + nf * 16 + lrow;
#pragma unroll
            for (int rg = 0; rg < 4; ++rg)
                s[((size_t)b << 20) + (size_t)(n + rg) * NTOK_ + m] = acc[mf][nf][rg];
        }
    }
}

// ---------------- 8. softmax in place: fp32 row -> [hi|lo] split planes ----------------
__global__ __launch_bounds__(256) void softmax_kernel(float* __restrict__ s) {
    size_t row = blockIdx.x;
    float* p = s + (row << 10);
    int tid = threadIdx.x;
    f32x4 v = *(const f32x4*)&p[tid * 4];
    __shared__ float redm[4], reds[4];
    float m = fmaxf(fmaxf(v[0], v[1]), fmaxf(v[2], v[3]));
#pragma unroll
    for (int off = 32; off; off >>= 1) m = fmaxf(m, __shfl_down(m, off));
    int wid = tid >> 6, lane = tid & 63;
    if (lane == 0) redm[wid] = m;
    __syncthreads();
    m = fmaxf(fmaxf(redm[0], redm[1]), fmaxf(redm[2], redm[3]));
#pragma unroll
    for (int j = 0; j < 4; ++j) v[j] = __expf(v[j] - m);
    float sum = v[0] + v[1] + v[2] + v[3];
#pragma unroll
    for (int off = 32; off; off >>= 1) sum += __shfl_down(sum, off);
    if (lane == 0) reds[wid] = sum;
    __syncthreads();
    float inv = 1.f / (reds[0] + reds[1] + reds[2] + reds[3]);
    union { ushort u[4]; ushort4 w; } hh, ll;
#pragma unroll
    for (int j = 0; j < 4; ++j) split2(v[j] * inv, hh.u[j], ll.u[j]);
    ushort* bp8 = (ushort*)p;  // row footprint: 2048 ushorts = [1024 hi | 1024 lo]
    *(ushort4*)&bp8[tid * 4] = hh.w;
    *(ushort4*)&bp8[1024 + tid * 4] = ll.w;
}

// ---------------- 9. out = attn @ vp + bsum + x, NCHW ----------------
__global__ __launch_bounds__(256) void gemm_out(
    const float* __restrict__ s,  // split planes inside rows
    const ushort* __restrict__ vpt_hi, const ushort* __restrict__ vpt_lo,
    const float* __restrict__ bsum, const float* __restrict__ x,
    float* __restrict__ out) {
    int ox = blockIdx.x, ny = blockIdx.y, b = blockIdx.z;
    const ushort* att = (const ushort*)s;
    const ushort* Ah = att + ((size_t)b * NTOK_ + ny * 128) * 2048;
    const ushort* Al = Ah + 1024;
    size_t bo = ((size_t)b * C_ + ox * 128) * NTOK_;
    f32x4 acc[4][4]; ACC_ZERO(acc);
    gemm_core_split(Ah, Al, 2048, vpt_hi + bo, vpt_lo + bo, NTOK_, NTOK_, acc);

    int tid = threadIdx.x, wave = tid >> 6, lane = tid & 63;
    int wm = wave >> 1, wn = wave & 1, lrow = lane & 15, lk = lane >> 4;
#pragma unroll
    for (int mf = 0; mf < 4; ++mf) {
        int n0l = ny * 128 + wm * 64 + mf * 16 + 4 * lk;
#pragma unroll
        for (int nf = 0; nf < 4; ++nf) {
            int oc = ox * 128 + wn * 64 + nf * 16 + lrow;
            size_t base = ((size_t)b * C_ + oc) * NTOK_ + n0l;
            f32x4 xr = *(const f32x4*)&x[base];
            float bs = bsum[oc];
            f32x4 rv;
#pragma unroll
            for (int rg = 0; rg < 4; ++rg) rv[rg] = acc[mf][nf][rg] + bs + xr[rg];
            *(f32x4*)&out[base] = rv;
        }
    }
}

extern "C" void kernel_launch(void* const* d_in, const int* in_sizes, int n_in,
                              void* d_out, int out_size, void* d_ws, size_t ws_size,
                              hipStream_t stream) {
    const float* x  = (const float*)d_in[0];
    const float* gw = (const float*)d_in[1];
    const float* gb = (const float*)d_in[2];
    const float* wq = (const float*)d_in[3];
    const float* bq = (const float*)d_in[4];
    const float* wk = (const float*)d_in[5];
    const float* bk = (const float*)d_in[6];
    const float* wv = (const float*)d_in[7];
    const float* bv = (const float*)d_in[8];
    const float* wp = (const float*)d_in[9];
    const float* bp = (const float*)d_in[10];
    float* out = (float*)d_out;

    const size_t TOKC2 = (size_t)B_ * NTOK_ * C_ * 2;   // bytes of one bf16 plane (16 MB)
    const size_t W2 = (size_t)C_ * C_ * 2;               // 512 KB
    char* w = (char*)d_ws;
    auto carve = [&](size_t bytes) { char* p = w; w += (bytes + 255) & ~(size_t)255; return p; };

    float*  scale_a = (float*)carve(B_ * C_ * 4);
    float*  bias_a  = (float*)carve(B_ * C_ * 4);
    float*  bsumv   = (float*)carve(C_ * 4);
    ushort* h_hi    = (ushort*)carve(TOKC2);
    ushort* h_lo    = (ushort*)carve(TOKC2);
    ushort* wqh     = (ushort*)carve(W2);
    ushort* wql     = (ushort*)carve(W2);
    ushort* wkh     = (ushort*)carve(W2);
    ushort* wkl     = (ushort*)carve(W2);
    ushort* weh     = (ushort*)carve(W2);
    ushort* wel     = (ushort*)carve(W2);
    ushort* q_hi    = (ushort*)carve(TOKC2);
    ushort* q_lo    = (ushort*)carve(TOKC2);
    ushort* k_hi    = (ushort*)carve(TOKC2);
    ushort* k_lo    = (ushort*)carve(TOKC2);
    ushort* vpt_hi  = (ushort*)carve(TOKC2);
    ushort* vpt_lo  = (ushort*)carve(TOKC2);
    float*  scores  = (float*)carve((size_t)B_ * NTOK_ * NTOK_ * 4);  // 64 MB
    if ((size_t)(w - (char*)d_ws) > ws_size) return;  // ws too small: fail loud, no OOB

    gn_stats_kernel<<<B_ * 32, 256, 0, stream>>>(x, gw, gb, scale_a, bias_a);
    prep_h_kernel<<<dim3(8, 16, B_), 256, 0, stream>>>(x, scale_a, bias_a, h_hi, h_lo);
    prep_w_kernel<<<256, 256, 0, stream>>>(wq, wk, wqh, wql, wkh, wkl);
    weff_kernel<<<dim3(8, 8), 256, 0, stream>>>(wp, wv, weh, wel);
    bsum_kernel<<<2, 256, 0, stream>>>(wp, bv, bp, bsumv);
    gemm_qkv<<<dim3(12, 128), 256, 0, stream>>>(h_hi, h_lo, wqh, wql, wkh, wkl,
                                                weh, wel, bq, bk,
                                                q_hi, q_lo, k_hi, k_lo, vpt_hi, vpt_lo);
    gemm_scores<<<dim3(8, 8, B_), 256, 0, stream>>>(q_hi, q_lo, k_hi, k_lo, scores);
    softmax_kernel<<<B_ * NTOK_, 256, 0, stream>>>(scores);
    gemm_out<<<dim3(4, 8, B_), 256, 0, stream>>>(scores, vpt_hi, vpt_lo, bsumv, x, out);
}

// Round 5
// 380.559 us; speedup vs baseline: 1.1146x; 1.1146x over previous
//
#include <hip/hip_runtime.h>
#include <hip/hip_bf16.h>

// AttnBlock: GroupNorm + single-head attention (N=1024 tokens, C=512) + residual.
// B=16. GEMMs on MFMA via SPLIT-BF16 (hi+lo; C = Ah*Bh + Ah*Bl + Al*Bh).
// R4 changes vs passing R3 kernel (424 us, absmax 0.0156):
//  - gemm core staging: reg-staged dbuf (64KB LDS, 2 blk/CU, MfmaUtil 30%) ->
//    global_load_lds width=16, single-buffer 32KB, m97 2-barrier loop.
//    LDS READ path unchanged (proven); writes produced by pre-swizzled per-lane
//    global source: LDS(row,off) holds global (row, off ^ ((row&7)<<4)).
//  - gemm_out: attn A-operand hi-plane only (2 MFMA terms; P in [0,1], adds
//    ~6e-4 abs err). softmax writes hi plane only.
//  - XCD-chunked bijective block swizzle on the 3 GEMMs (grids %8==0).
//  - bsum wave-parallel.

#define B_ 16
#define C_ 512
#define NTOK_ 1024
#define CPG_ 16
#define EPS_ 1e-5f
#define QSCALE_ 0.04419417382415922f  // 512^-0.5

typedef __attribute__((ext_vector_type(8))) short short8;  // 8 bf16 = 4 VGPR
typedef __attribute__((ext_vector_type(4))) float f32x4;
typedef const void __attribute__((address_space(1)))* gas1_t;
typedef void __attribute__((address_space(3)))* las3_t;

// ---- bf16 split helpers (RNE) ----
__device__ __forceinline__ ushort bf16_rne(float x) {
    union { float f; unsigned u; } v; v.f = x;
    unsigned r = v.u + 0x7fffu + ((v.u >> 16) & 1u);
    return (ushort)(r >> 16);
}
__device__ __forceinline__ float bf2f(ushort h) {
    union { unsigned u; float f; } v; v.u = (unsigned)h << 16; return v.f;
}
__device__ __forceinline__ void split2(float x, ushort& hi, ushort& lo) {
    hi = bf16_rne(x);
    lo = bf16_rne(x - bf2f(hi));
}

// =================== split-bf16 MFMA GEMM core ===================
// C[128 x 128] += A · B^T (rows of B = output cols), hi/lo planes, K%32==0.
// NTERMS==3: full split. NTERMS==2: A hi-only (pass Al=Ah; lo LDS slots get
// duplicate hi bytes, never read).
// LDS: single 32KB buffer. A tile rows [0,128) at row*128B, B at +16KB.
// Within a row: 4 chunks of (16B hi | 16B lo), byte pos XOR ((row&7)<<4).
// Staged via global_load_lds: wave w stages 8 chunks of 1024B; per-lane source
// row tr = (w&1)*64 + j*8 + (lane>>3), sel = (lane&7)^(lane>>3) -> plane=sel&1,
// k-16B-chunk=sel>>1 (constant per lane across j).
template<int NTERMS>
__device__ __forceinline__ void gemm_core(
    const ushort* __restrict__ Ah, const ushort* __restrict__ Al, int lda,
    const ushort* __restrict__ Bh, const ushort* __restrict__ Bl, int ldb,
    int K, f32x4 acc[4][4])
{
    __shared__ alignas(16) char ldsc[32768];
    const int tid  = threadIdx.x;
    const int wave = tid >> 6, lane = tid & 63;
    const int wm = wave >> 1, wn = wave & 1;
    const int lrow = lane & 15, lk = lane >> 4;

    // staging: waves 0,1 -> A rows [0,64)/[64,128); waves 2,3 -> B same split
    const int isB = wave >> 1;
    const ushort* Ph = isB ? Bh : Ah;
    const ushort* Pl = isB ? Bl : Al;
    const int ld = isB ? ldb : lda;
    const int sel = (lane & 7) ^ (lane >> 3);
    const ushort* P = (sel & 1) ? Pl : Ph;
    const int tr0 = ((wave & 1) << 6) + (lane >> 3);
    const ushort* src0 = P + (size_t)tr0 * ld + ((sel >> 1) << 3);

    const int nsteps = K >> 5;
    for (int t = 0; t < nsteps; ++t) {
        const ushort* st = src0 + t * 32;
#pragma unroll
        for (int j = 0; j < 8; ++j) {
            __builtin_amdgcn_global_load_lds(
                (gas1_t)(st + (size_t)(j << 3) * ld),
                (las3_t)(ldsc + (((wave << 3) + j) << 10)),
                16, 0, 0);
        }
        __syncthreads();  // drains vmcnt(0): LDS tile complete for all waves

        short8 afh[4], afl[4], bfh[4], bfl[4];
#pragma unroll
        for (int m = 0; m < 4; ++m) {
            int row = wm * 64 + m * 16 + lrow;
            const char* base = ldsc + row * 128;
            int s = (row & 7) << 4;
            afh[m] = *(const short8*)(base + ((lk * 32) ^ s));
            if (NTERMS == 3)
                afl[m] = *(const short8*)(base + ((lk * 32 + 16) ^ s));
        }
#pragma unroll
        for (int n = 0; n < 4; ++n) {
            int row = wn * 64 + n * 16 + lrow;
            const char* base = ldsc + 16384 + row * 128;
            int s = (row & 7) << 4;
            bfh[n] = *(const short8*)(base + ((lk * 32) ^ s));
            bfl[n] = *(const short8*)(base + ((lk * 32 + 16) ^ s));
        }
#pragma unroll
        for (int m = 0; m < 4; ++m)
#pragma unroll
            for (int n = 0; n < 4; ++n) {
                acc[m][n] = __builtin_amdgcn_mfma_f32_16x16x32_bf16(afh[m], bfh[n], acc[m][n], 0, 0, 0);
                acc[m][n] = __builtin_amdgcn_mfma_f32_16x16x32_bf16(afh[m], bfl[n], acc[m][n], 0, 0, 0);
                if (NTERMS == 3)
                    acc[m][n] = __builtin_amdgcn_mfma_f32_16x16x32_bf16(afl[m], bfh[n], acc[m][n], 0, 0, 0);
            }
        __syncthreads();  // before next K-step overwrites the buffer
    }
}

#define ACC_ZERO(acc) do { \
    _Pragma("unroll") for (int m_ = 0; m_ < 4; ++m_) \
    _Pragma("unroll") for (int n_ = 0; n_ < 4; ++n_) \
        acc[m_][n_] = (f32x4){0.f, 0.f, 0.f, 0.f}; \
} while (0)

// ---------------- 1. GroupNorm stats ----------------
__global__ __launch_bounds__(256) void gn_stats_kernel(
    const float* __restrict__ x, const float* __restrict__ gw,
    const float* __restrict__ gb, float* __restrict__ scale_a,
    float* __restrict__ bias_a) {
    int bg = blockIdx.x;
    int b = bg >> 5, g = bg & 31;
    const float4* xp = (const float4*)(x + (size_t)(b * C_ + g * CPG_) * NTOK_);
    int tid = threadIdx.x;
    float s = 0.f, ss = 0.f;
    for (int i = tid; i < 4096; i += 256) {
        float4 v = xp[i];
        s += v.x + v.y + v.z + v.w;
        ss += v.x * v.x + v.y * v.y + v.z * v.z + v.w * v.w;
    }
    __shared__ float red[8];
    __shared__ float smu, srstd;
#pragma unroll
    for (int off = 32; off; off >>= 1) {
        s += __shfl_down(s, off);
        ss += __shfl_down(ss, off);
    }
    int wid = tid >> 6, lane = tid & 63;
    if (lane == 0) { red[wid] = s; red[wid + 4] = ss; }
    __syncthreads();
    if (tid == 0) {
        float S = red[0] + red[1] + red[2] + red[3];
        float SS = red[4] + red[5] + red[6] + red[7];
        float mu = S * (1.f / 16384.f);
        float var = SS * (1.f / 16384.f) - mu * mu;
        smu = mu;
        srstd = rsqrtf(var + EPS_);
    }
    __syncthreads();
    if (tid < CPG_) {
        int c = g * CPG_ + tid;
        float sc = srstd * gw[c];
        scale_a[b * C_ + c] = sc;
        bias_a[b * C_ + c] = gb[c] - smu * sc;
    }
}

// ---------------- 2. prep_h: affine + transpose + split ----------------
__global__ __launch_bounds__(256) void prep_h_kernel(
    const float* __restrict__ x, const float* __restrict__ scale_a,
    const float* __restrict__ bias_a, ushort* __restrict__ h_hi,
    ushort* __restrict__ h_lo) {
    __shared__ ushort sh[64][72], sl[64][72];
    int tid = threadIdx.x;
    int ct = blockIdx.x, nt = blockIdx.y, b = blockIdx.z;
    int cl = tid >> 2, nq = tid & 3;
    int c = ct * 64 + cl;
    const float* xp = x + (((size_t)b * C_ + c) << 10) + nt * 64;
    float sc = scale_a[b * C_ + c], bi = bias_a[b * C_ + c];
#pragma unroll
    for (int i = 0; i < 4; ++i) {
        f32x4 v = *(const f32x4*)&xp[nq * 16 + i * 4];
#pragma unroll
        for (int j = 0; j < 4; ++j) {
            ushort h, l;
            split2(v[j] * sc + bi, h, l);
            sh[cl][nq * 16 + i * 4 + j] = h;
            sl[cl][nq * 16 + i * 4 + j] = l;
        }
    }
    __syncthreads();
    int nl = tid >> 2, cq = tid & 3;
    size_t ob = (((size_t)b << 10) + nt * 64 + nl) * C_ + ct * 64 + cq * 16;
    union { ushort u[8]; uint4 v; } p0, p1;
#pragma unroll
    for (int j = 0; j < 8; ++j) { p0.u[j] = sh[cq * 16 + j][nl]; p1.u[j] = sh[cq * 16 + 8 + j][nl]; }
    *(uint4*)&h_hi[ob] = p0.v;  *(uint4*)&h_hi[ob + 8] = p1.v;
#pragma unroll
    for (int j = 0; j < 8; ++j) { p0.u[j] = sl[cq * 16 + j][nl]; p1.u[j] = sl[cq * 16 + 8 + j][nl]; }
    *(uint4*)&h_lo[ob] = p0.v;  *(uint4*)&h_lo[ob + 8] = p1.v;
}

// ---------------- 3. prep_w: split wq, wk ----------------
__global__ __launch_bounds__(256) void prep_w_kernel(
    const float* __restrict__ wq, const float* __restrict__ wk,
    ushort* __restrict__ wqh, ushort* __restrict__ wql,
    ushort* __restrict__ wkh, ushort* __restrict__ wkl) {
    int i = blockIdx.x * 256 + threadIdx.x;
    union { ushort u[4]; ushort4 v; } h, l;
    f32x4 a = ((const f32x4*)wq)[i];
#pragma unroll
    for (int j = 0; j < 4; ++j) split2(a[j], h.u[j], l.u[j]);
    ((ushort4*)wqh)[i] = h.v;  ((ushort4*)wql)[i] = l.v;
    f32x4 b = ((const f32x4*)wk)[i];
#pragma unroll
    for (int j = 0; j < 4; ++j) split2(b[j], h.u[j], l.u[j]);
    ((ushort4*)wkh)[i] = h.v;  ((ushort4*)wkl)[i] = l.v;
}

// ---------------- 4. Weff = wp @ wv (fp32) -> split ----------------
__global__ __launch_bounds__(256) void weff_kernel(
    const float* __restrict__ wp, const float* __restrict__ wv,
    ushort* __restrict__ weh, ushort* __restrict__ wel) {
    __shared__ float As[16][68], Bs[16][68];
    int tid = threadIdx.x, ty = tid >> 4, tx = tid & 15;
    int c0 = blockIdx.x << 6, p0 = blockIdx.y << 6;
    int a_row = tid >> 2, a_kq = tid & 3;
    int b_m = tid >> 4, b_cq = tid & 15;
    float acc[4][4] = {};
    for (int k0 = 0; k0 < C_; k0 += 16) {
        f32x4 a4 = *(const f32x4*)&wp[(size_t)(p0 + a_row) * C_ + k0 + a_kq * 4];
        As[a_kq * 4 + 0][a_row] = a4[0]; As[a_kq * 4 + 1][a_row] = a4[1];
        As[a_kq * 4 + 2][a_row] = a4[2]; As[a_kq * 4 + 3][a_row] = a4[3];
        *(f32x4*)&Bs[b_m][b_cq * 4] =
            *(const f32x4*)&wv[(size_t)(k0 + b_m) * C_ + c0 + b_cq * 4];
        __syncthreads();
#pragma unroll
        for (int kk = 0; kk < 16; ++kk) {
            f32x4 av = *(const f32x4*)&As[kk][ty << 2];
            f32x4 bv = *(const f32x4*)&Bs[kk][tx << 2];
#pragma unroll
            for (int i = 0; i < 4; ++i)
#pragma unroll
                for (int j = 0; j < 4; ++j) acc[i][j] += av[i] * bv[j];
        }
        __syncthreads();
    }
#pragma unroll
    for (int i = 0; i < 4; ++i) {
        union { ushort u[4]; ushort4 v; } hh, ll;
#pragma unroll
        for (int j = 0; j < 4; ++j) split2(acc[i][j], hh.u[j], ll.u[j]);
        size_t o = (size_t)(p0 + ty * 4 + i) * C_ + c0 + tx * 4;
        *(ushort4*)&weh[o] = hh.v;  *(ushort4*)&wel[o] = ll.v;
    }
}

// ---------------- 5. bsum[p] = bp[p] + sum_o wp[p][o]*bv[o] (wave-parallel) ----------------
__global__ __launch_bounds__(256) void bsum_kernel(
    const float* __restrict__ wp, const float* __restrict__ bv,
    const float* __restrict__ bp, float* __restrict__ bsum) {
    int p = blockIdx.x * 4 + (threadIdx.x >> 6);   // grid 128 -> p in [0,512)
    int lane = threadIdx.x & 63;
    const float* row = wp + (size_t)p * C_;
    f32x4 w0 = *(const f32x4*)&row[lane * 8];
    f32x4 w1 = *(const f32x4*)&row[lane * 8 + 4];
    f32x4 b0 = *(const f32x4*)&bv[lane * 8];
    f32x4 b1 = *(const f32x4*)&bv[lane * 8 + 4];
    float s = w0[0]*b0[0] + w0[1]*b0[1] + w0[2]*b0[2] + w0[3]*b0[3]
            + w1[0]*b1[0] + w1[1]*b1[1] + w1[2]*b1[2] + w1[3]*b1[3];
#pragma unroll
    for (int off = 32; off; off >>= 1) s += __shfl_down(s, off);
    if (lane == 0) bsum[p] = bp[p] + s;
}

// ---------------- 6. qkv GEMM (q, k, vp^T from h) ----------------
__global__ __launch_bounds__(256) void gemm_qkv(
    const ushort* __restrict__ h_hi, const ushort* __restrict__ h_lo,
    const ushort* __restrict__ wqh, const ushort* __restrict__ wql,
    const ushort* __restrict__ wkh, const ushort* __restrict__ wkl,
    const ushort* __restrict__ weh, const ushort* __restrict__ wel,
    const float* __restrict__ bq, const float* __restrict__ bk,
    ushort* __restrict__ q_hi, ushort* __restrict__ q_lo,
    ushort* __restrict__ k_hi, ushort* __restrict__ k_lo,
    ushort* __restrict__ vpt_hi, ushort* __restrict__ vpt_lo) {
    // XCD-chunked bijective swizzle (nwg=1536, %8==0)
    int D = blockIdx.x + 12 * blockIdx.y;
    int L = ((D & 7) * 192) + (D >> 3);
    int lx = L % 12, mt = L / 12;
    int wsel = lx >> 2, ct = lx & 3;

    const ushort *Bh, *Bl;
    const float* bias = nullptr;
    if (wsel == 0)      { Bh = wqh; Bl = wql; bias = bq; }
    else if (wsel == 1) { Bh = wkh; Bl = wkl; bias = bk; }
    else                { Bh = weh; Bl = wel; }

    f32x4 acc[4][4]; ACC_ZERO(acc);
    gemm_core<3>(h_hi + (size_t)mt * 128 * C_, h_lo + (size_t)mt * 128 * C_, C_,
                 Bh + (size_t)ct * 128 * C_,   Bl + (size_t)ct * 128 * C_,   C_,
                 C_, acc);

    int tid = threadIdx.x, wave = tid >> 6, lane = tid & 63;
    int wm = wave >> 1, wn = wave & 1, lrow = lane & 15, lk = lane >> 4;

    if (wsel < 2) {
        ushort* oh = wsel ? k_hi : q_hi;
        ushort* ol = wsel ? k_lo : q_lo;
        float scale = wsel ? 1.f : QSCALE_;
#pragma unroll
        for (int mf = 0; mf < 4; ++mf) {
            int gm = mt * 128 + wm * 64 + mf * 16 + 4 * lk;
#pragma unroll
            for (int nf = 0; nf < 4; ++nf) {
                int gc = ct * 128 + wn * 64 + nf * 16 + lrow;
                float bi = bias[gc];
#pragma unroll
                for (int rg = 0; rg < 4; ++rg) {
                    ushort h, l;
                    split2((acc[mf][nf][rg] + bi) * scale, h, l);
                    size_t o = (size_t)(gm + rg) * C_ + gc;
                    oh[o] = h; ol[o] = l;
                }
            }
        }
    } else {
#pragma unroll
        for (int mf = 0; mf < 4; ++mf) {
            int gm0 = mt * 128 + wm * 64 + mf * 16 + 4 * lk;
            int b = gm0 >> 10, nl = gm0 & 1023;
#pragma unroll
            for (int nf = 0; nf < 4; ++nf) {
                int p = ct * 128 + wn * 64 + nf * 16 + lrow;
                union { ushort u[4]; ushort4 v; } hv, lv;
#pragma unroll
                for (int rg = 0; rg < 4; ++rg) split2(acc[mf][nf][rg], hv.u[rg], lv.u[rg]);
                size_t o = ((size_t)b * C_ + p) * NTOK_ + nl;
                *(ushort4*)&vpt_hi[o] = hv.v;
                *(ushort4*)&vpt_lo[o] = lv.v;
            }
        }
    }
}

// ---------------- 7. scores = q @ k^T (per batch), fp32 out ----------------
__global__ __launch_bounds__(256) void gemm_scores(
    const ushort* __restrict__ q_hi, const ushort* __restrict__ q_lo,
    const ushort* __restrict__ k_hi, const ushort* __restrict__ k_lo,
    float* __restrict__ s) {
    // swizzle (nwg=1024)
    int D = blockIdx.x + (blockIdx.y << 3) + (blockIdx.z << 6);
    int L = ((D & 7) << 7) + (D >> 3);
    int nx = L & 7, my = (L >> 3) & 7, b = L >> 6;

    size_t ao = ((size_t)b * NTOK_ + my * 128) * C_;
    size_t bo = ((size_t)b * NTOK_ + nx * 128) * C_;
    f32x4 acc[4][4]; ACC_ZERO(acc);
    gemm_core<3>(q_hi + ao, q_lo + ao, C_, k_hi + bo, k_lo + bo, C_, C_, acc);

    int tid = threadIdx.x, wave = tid >> 6, lane = tid & 63;
    int wm = wave >> 1, wn = wave & 1, lrow = lane & 15, lk = lane >> 4;
#pragma unroll
    for (int mf = 0; mf < 4; ++mf) {
        int n = my * 128 + wm * 64 + mf * 16 + 4 * lk;
#pragma unroll
        for (int nf = 0; nf < 4; ++nf) {
            int m = nx * 128 + wn * 64 + nf * 16 + lrow;
#pragma unroll
            for (int rg = 0; rg < 4; ++rg)
                s[((size_t)b << 20) + (size_t)(n + rg) * NTOK_ + m] = acc[mf][nf][rg];
        }
    }
}

// ---------------- 8. softmax: fp32 row -> bf16 hi plane only ----------------
__global__ __launch_bounds__(256) void softmax_kernel(float* __restrict__ s) {
    size_t row = blockIdx.x;
    float* p = s + (row << 10);
    int tid = threadIdx.x;
    f32x4 v = *(const f32x4*)&p[tid * 4];
    __shared__ float redm[4], reds[4];
    float m = fmaxf(fmaxf(v[0], v[1]), fmaxf(v[2], v[3]));
#pragma unroll
    for (int off = 32; off; off >>= 1) m = fmaxf(m, __shfl_down(m, off));
    int wid = tid >> 6, lane = tid & 63;
    if (lane == 0) redm[wid] = m;
    __syncthreads();
    m = fmaxf(fmaxf(redm[0], redm[1]), fmaxf(redm[2], redm[3]));
#pragma unroll
    for (int j = 0; j < 4; ++j) v[j] = __expf(v[j] - m);
    float sum = v[0] + v[1] + v[2] + v[3];
#pragma unroll
    for (int off = 32; off; off >>= 1) sum += __shfl_down(sum, off);
    if (lane == 0) reds[wid] = sum;
    __syncthreads();
    float inv = 1.f / (reds[0] + reds[1] + reds[2] + reds[3]);
    union { ushort u[4]; ushort4 w; } hh;
#pragma unroll
    for (int j = 0; j < 4; ++j) hh.u[j] = bf16_rne(v[j] * inv);
    ushort* bp8 = (ushort*)p;  // row = 2048 ushorts; hi plane in [0,1024)
    *(ushort4*)&bp8[tid * 4] = hh.w;
}

// ---------------- 9. out = attn @ vp + bsum + x, NCHW ----------------
__global__ __launch_bounds__(256) void gemm_out(
    const float* __restrict__ s,
    const ushort* __restrict__ vpt_hi, const ushort* __restrict__ vpt_lo,
    const float* __restrict__ bsum, const float* __restrict__ x,
    float* __restrict__ out) {
    // swizzle (nwg=512)
    int D = blockIdx.x + (blockIdx.y << 2) + (blockIdx.z << 5);
    int L = ((D & 7) << 6) + (D >> 3);
    int ox = L & 3, ny = (L >> 2) & 7, b = L >> 5;

    const ushort* att = (const ushort*)s;
    const ushort* Ah = att + ((size_t)b * NTOK_ + ny * 128) * 2048;
    size_t bo = ((size_t)b * C_ + ox * 128) * NTOK_;
    f32x4 acc[4][4]; ACC_ZERO(acc);
    // A hi-only (NTERMS=2): pass Al=Ah so staging lo-lanes load valid dup bytes
    gemm_core<2>(Ah, Ah, 2048, vpt_hi + bo, vpt_lo + bo, NTOK_, NTOK_, acc);

    int tid = threadIdx.x, wave = tid >> 6, lane = tid & 63;
    int wm = wave >> 1, wn = wave & 1, lrow = lane & 15, lk = lane >> 4;
#pragma unroll
    for (int mf = 0; mf < 4; ++mf) {
        int n0l = ny * 128 + wm * 64 + mf * 16 + 4 * lk;
#pragma unroll
        for (int nf = 0; nf < 4; ++nf) {
            int oc = ox * 128 + wn * 64 + nf * 16 + lrow;
            size_t base = ((size_t)b * C_ + oc) * NTOK_ + n0l;
            f32x4 xr = *(const f32x4*)&x[base];
            float bs = bsum[oc];
            f32x4 rv;
#pragma unroll
            for (int rg = 0; rg < 4; ++rg) rv[rg] = acc[mf][nf][rg] + bs + xr[rg];
            *(f32x4*)&out[base] = rv;
        }
    }
}

extern "C" void kernel_launch(void* const* d_in, const int* in_sizes, int n_in,
                              void* d_out, int out_size, void* d_ws, size_t ws_size,
                              hipStream_t stream) {
    const float* x  = (const float*)d_in[0];
    const float* gw = (const float*)d_in[1];
    const float* gb = (const float*)d_in[2];
    const float* wq = (const float*)d_in[3];
    const float* bq = (const float*)d_in[4];
    const float* wk = (const float*)d_in[5];
    const float* bk = (const float*)d_in[6];
    const float* wv = (const float*)d_in[7];
    const float* bv = (const float*)d_in[8];
    const float* wp = (const float*)d_in[9];
    const float* bp = (const float*)d_in[10];
    float* out = (float*)d_out;

    const size_t TOKC2 = (size_t)B_ * NTOK_ * C_ * 2;   // one bf16 plane (16 MB)
    const size_t W2 = (size_t)C_ * C_ * 2;               // 512 KB
    char* w = (char*)d_ws;
    auto carve = [&](size_t bytes) { char* p = w; w += (bytes + 255) & ~(size_t)255; return p; };

    float*  scale_a = (float*)carve(B_ * C_ * 4);
    float*  bias_a  = (float*)carve(B_ * C_ * 4);
    float*  bsumv   = (float*)carve(C_ * 4);
    ushort* h_hi    = (ushort*)carve(TOKC2);
    ushort* h_lo    = (ushort*)carve(TOKC2);
    ushort* wqh     = (ushort*)carve(W2);
    ushort* wql     = (ushort*)carve(W2);
    ushort* wkh     = (ushort*)carve(W2);
    ushort* wkl     = (ushort*)carve(W2);
    ushort* weh     = (ushort*)carve(W2);
    ushort* wel     = (ushort*)carve(W2);
    ushort* q_hi    = (ushort*)carve(TOKC2);
    ushort* q_lo    = (ushort*)carve(TOKC2);
    ushort* k_hi    = (ushort*)carve(TOKC2);
    ushort* k_lo    = (ushort*)carve(TOKC2);
    ushort* vpt_hi  = (ushort*)carve(TOKC2);
    ushort* vpt_lo  = (ushort*)carve(TOKC2);
    float*  scores  = (float*)carve((size_t)B_ * NTOK_ * NTOK_ * 4);  // 64 MB
    if ((size_t)(w - (char*)d_ws) > ws_size) return;

    gn_stats_kernel<<<B_ * 32, 256, 0, stream>>>(x, gw, gb, scale_a, bias_a);
    prep_h_kernel<<<dim3(8, 16, B_), 256, 0, stream>>>(x, scale_a, bias_a, h_hi, h_lo);
    prep_w_kernel<<<256, 256, 0, stream>>>(wq, wk, wqh, wql, wkh, wkl);
    weff_kernel<<<dim3(8, 8), 256, 0, stream>>>(wp, wv, weh, wel);
    bsum_kernel<<<128, 256, 0, stream>>>(wp, bv, bp, bsumv);
    gemm_qkv<<<dim3(12, 128), 256, 0, stream>>>(h_hi, h_lo, wqh, wql, wkh, wkl,
                                                weh, wel, bq, bk,
                                                q_hi, q_lo, k_hi, k_lo, vpt_hi, vpt_lo);
    gemm_scores<<<dim3(8, 8, B_), 256, 0, stream>>>(q_hi, q_lo, k_hi, k_lo, scores);
    softmax_kernel<<<B_ * NTOK_, 256, 0, stream>>>(scores);
    gemm_out<<<dim3(4, 8, B_), 256, 0, stream>>>(scores, vpt_hi, vpt_lo, bsumv, x, out);
}

// Round 6
// 256.717 us; speedup vs baseline: 1.6523x; 1.4824x over previous
//
#include <hip/hip_runtime.h>
#include <hip/hip_bf16.h>

// AttnBlock: GroupNorm + single-head attention (N=1024 tokens, C=512) + residual.
// B=16. R6: all GEMM operands SINGLE-PLANE FP16 (10-bit mantissa; rel err 2^-11).
// R5 post-mortem: split-bf16 3-term ran at the m97-structure ceiling (~734 TF
// effective) -> the 3x term tax was the cost. fp16 single-plane cuts MFMA work
// 3x (qkv/scores) and 2x (out), halves staging bytes, and is MORE accurate on
// the attn path than R5's bf16-hi attn (2^-11 vs 2^-8).
//
// GEMM core: 128x128 tile, BK=64, single 32KB LDS buffer, m97 2-barrier loop,
// global_load_lds width=16 with pre-swizzled per-lane source. LDS rows 128B
// (64 f16); 16B chunk c of row placed at slot c^(row&7) -> ds_read_b128 2-way
// only. 4 waves x (4x4 frags x 2 k-halves) = 32 MFMA (16x16x32 f16) per step.

#define B_ 16
#define C_ 512
#define NTOK_ 1024
#define CPG_ 16
#define EPS_ 1e-5f
#define QSCALE_ 0.04419417382415922f  // 512^-0.5

typedef __attribute__((ext_vector_type(8))) _Float16 f16x8;  // 4 VGPR
typedef __attribute__((ext_vector_type(4))) float f32x4;
typedef const void __attribute__((address_space(1)))* gas1_t;
typedef void __attribute__((address_space(3)))* las3_t;

__device__ __forceinline__ ushort f2h(float x) {
    union { _Float16 h; ushort u; } c; c.h = (_Float16)x; return c.u;
}

// =================== fp16 MFMA GEMM core ===================
// C[128 x 128] += A · B^T (rows of B = output cols), fp16 (as ushort*), K%64==0.
// acc[m][n]: wave (wm,wn); C row = wm*64+m*16+4*lk+reg, col = wn*64+n*16+lrow.
__device__ __forceinline__ void gemm_core_f16(
    const ushort* __restrict__ A, int lda,
    const ushort* __restrict__ B, int ldb,
    int K, f32x4 acc[4][4])
{
    __shared__ alignas(16) char ldsc[32768];  // A [0,16K), B [16K,32K)
    const int tid  = threadIdx.x;
    const int wave = tid >> 6, lane = tid & 63;
    const int wm = wave >> 1, wn = wave & 1;
    const int lrow = lane & 15, lk = lane >> 4;

    // staging: waves 0,1 -> A rows [0,64)/[64,128); waves 2,3 -> B same split.
    // 1KB chunk j covers 8 rows; lane writes LDS unit u=(chunkrow+l>>3)*8+(l&7);
    // source chunk there = (l&7)^(row&7) = (l&7)^(l>>3) = sel (row%8 == l>>3).
    const int isB = wave >> 1;
    const ushort* P = isB ? B : A;
    const int ld = isB ? ldb : lda;
    const int sel = (lane & 7) ^ (lane >> 3);
    const int rowbase = ((wave & 1) << 6) + (lane >> 3);
    const ushort* src0 = P + (size_t)rowbase * ld + sel * 8;
    char* dst0 = ldsc + (isB << 14) + ((wave & 1) << 13);

    const int nsteps = K >> 6;
    for (int t = 0; t < nsteps; ++t) {
        const ushort* st = src0 + t * 64;
#pragma unroll
        for (int j = 0; j < 8; ++j) {
            __builtin_amdgcn_global_load_lds(
                (gas1_t)(st + (size_t)(j << 3) * ld),
                (las3_t)(dst0 + (j << 10)), 16, 0, 0);
        }
        __syncthreads();  // vmcnt(0)+lgkmcnt(0) drain: tile visible to all

        f16x8 af[4][2], bf[4][2];
#pragma unroll
        for (int m = 0; m < 4; ++m) {
            int row = wm * 64 + m * 16 + lrow;
            const char* base = ldsc + row * 128;
#pragma unroll
            for (int ks = 0; ks < 2; ++ks) {
                int c = ks * 4 + lk;
                af[m][ks] = *(const f16x8*)(base + ((c ^ (row & 7)) << 4));
            }
        }
#pragma unroll
        for (int n = 0; n < 4; ++n) {
            int row = wn * 64 + n * 16 + lrow;
            const char* base = ldsc + 16384 + row * 128;
#pragma unroll
            for (int ks = 0; ks < 2; ++ks) {
                int c = ks * 4 + lk;
                bf[n][ks] = *(const f16x8*)(base + ((c ^ (row & 7)) << 4));
            }
        }
#pragma unroll
        for (int m = 0; m < 4; ++m)
#pragma unroll
            for (int n = 0; n < 4; ++n) {
                acc[m][n] = __builtin_amdgcn_mfma_f32_16x16x32_f16(af[m][0], bf[n][0], acc[m][n], 0, 0, 0);
                acc[m][n] = __builtin_amdgcn_mfma_f32_16x16x32_f16(af[m][1], bf[n][1], acc[m][n], 0, 0, 0);
            }
        __syncthreads();  // reads done before next step overwrites buffer
    }
}

#define ACC_ZERO(acc) do { \
    _Pragma("unroll") for (int m_ = 0; m_ < 4; ++m_) \
    _Pragma("unroll") for (int n_ = 0; n_ < 4; ++n_) \
        acc[m_][n_] = (f32x4){0.f, 0.f, 0.f, 0.f}; \
} while (0)

// ---------------- 1. GroupNorm stats ----------------
__global__ __launch_bounds__(256) void gn_stats_kernel(
    const float* __restrict__ x, const float* __restrict__ gw,
    const float* __restrict__ gb, float* __restrict__ scale_a,
    float* __restrict__ bias_a) {
    int bg = blockIdx.x;
    int b = bg >> 5, g = bg & 31;
    const float4* xp = (const float4*)(x + (size_t)(b * C_ + g * CPG_) * NTOK_);
    int tid = threadIdx.x;
    float s = 0.f, ss = 0.f;
    for (int i = tid; i < 4096; i += 256) {
        float4 v = xp[i];
        s += v.x + v.y + v.z + v.w;
        ss += v.x * v.x + v.y * v.y + v.z * v.z + v.w * v.w;
    }
    __shared__ float red[8];
    __shared__ float smu, srstd;
#pragma unroll
    for (int off = 32; off; off >>= 1) {
        s += __shfl_down(s, off);
        ss += __shfl_down(ss, off);
    }
    int wid = tid >> 6, lane = tid & 63;
    if (lane == 0) { red[wid] = s; red[wid + 4] = ss; }
    __syncthreads();
    if (tid == 0) {
        float S = red[0] + red[1] + red[2] + red[3];
        float SS = red[4] + red[5] + red[6] + red[7];
        float mu = S * (1.f / 16384.f);
        float var = SS * (1.f / 16384.f) - mu * mu;
        smu = mu;
        srstd = rsqrtf(var + EPS_);
    }
    __syncthreads();
    if (tid < CPG_) {
        int c = g * CPG_ + tid;
        float sc = srstd * gw[c];
        scale_a[b * C_ + c] = sc;
        bias_a[b * C_ + c] = gb[c] - smu * sc;
    }
}

// ---------------- 2. prep_h: affine + transpose -> h fp16 [b][n][c] ----------------
__global__ __launch_bounds__(256) void prep_h_kernel(
    const float* __restrict__ x, const float* __restrict__ scale_a,
    const float* __restrict__ bias_a, ushort* __restrict__ h16) {
    __shared__ ushort sh[64][72];
    int tid = threadIdx.x;
    int ct = blockIdx.x, nt = blockIdx.y, b = blockIdx.z;
    int cl = tid >> 2, nq = tid & 3;
    int c = ct * 64 + cl;
    const float* xp = x + (((size_t)b * C_ + c) << 10) + nt * 64;
    float sc = scale_a[b * C_ + c], bi = bias_a[b * C_ + c];
#pragma unroll
    for (int i = 0; i < 4; ++i) {
        f32x4 v = *(const f32x4*)&xp[nq * 16 + i * 4];
#pragma unroll
        for (int j = 0; j < 4; ++j)
            sh[cl][nq * 16 + i * 4 + j] = f2h(v[j] * sc + bi);
    }
    __syncthreads();
    int nl = tid >> 2, cq = tid & 3;
    size_t ob = (((size_t)b << 10) + nt * 64 + nl) * C_ + ct * 64 + cq * 16;
    union { ushort u[8]; uint4 v; } p0, p1;
#pragma unroll
    for (int j = 0; j < 8; ++j) { p0.u[j] = sh[cq * 16 + j][nl]; p1.u[j] = sh[cq * 16 + 8 + j][nl]; }
    *(uint4*)&h16[ob] = p0.v;  *(uint4*)&h16[ob + 8] = p1.v;
}

// ---------------- 3. prep_w: wq, wk -> fp16 ----------------
__global__ __launch_bounds__(256) void prep_w_kernel(
    const float* __restrict__ wq, const float* __restrict__ wk,
    ushort* __restrict__ wq16, ushort* __restrict__ wk16) {
    int i = blockIdx.x * 256 + threadIdx.x;  // one float4 of each matrix
    union { ushort u[4]; ushort4 v; } h;
    f32x4 a = ((const f32x4*)wq)[i];
#pragma unroll
    for (int j = 0; j < 4; ++j) h.u[j] = f2h(a[j]);
    ((ushort4*)wq16)[i] = h.v;
    f32x4 b = ((const f32x4*)wk)[i];
#pragma unroll
    for (int j = 0; j < 4; ++j) h.u[j] = f2h(b[j]);
    ((ushort4*)wk16)[i] = h.v;
}

// ---------------- 4. Weff = wp @ wv (fp32 VALU) -> fp16 ----------------
__global__ __launch_bounds__(256) void weff_kernel(
    const float* __restrict__ wp, const float* __restrict__ wv,
    ushort* __restrict__ we16) {
    __shared__ float As[16][68], Bs[16][68];
    int tid = threadIdx.x, ty = tid >> 4, tx = tid & 15;
    int c0 = blockIdx.x << 6, p0 = blockIdx.y << 6;
    int a_row = tid >> 2, a_kq = tid & 3;
    int b_m = tid >> 4, b_cq = tid & 15;
    float acc[4][4] = {};
    for (int k0 = 0; k0 < C_; k0 += 16) {
        f32x4 a4 = *(const f32x4*)&wp[(size_t)(p0 + a_row) * C_ + k0 + a_kq * 4];
        As[a_kq * 4 + 0][a_row] = a4[0]; As[a_kq * 4 + 1][a_row] = a4[1];
        As[a_kq * 4 + 2][a_row] = a4[2]; As[a_kq * 4 + 3][a_row] = a4[3];
        *(f32x4*)&Bs[b_m][b_cq * 4] =
            *(const f32x4*)&wv[(size_t)(k0 + b_m) * C_ + c0 + b_cq * 4];
        __syncthreads();
#pragma unroll
        for (int kk = 0; kk < 16; ++kk) {
            f32x4 av = *(const f32x4*)&As[kk][ty << 2];
            f32x4 bv = *(const f32x4*)&Bs[kk][tx << 2];
#pragma unroll
            for (int i = 0; i < 4; ++i)
#pragma unroll
                for (int j = 0; j < 4; ++j) acc[i][j] += av[i] * bv[j];
        }
        __syncthreads();
    }
#pragma unroll
    for (int i = 0; i < 4; ++i) {
        union { ushort u[4]; ushort4 v; } hh;
#pragma unroll
        for (int j = 0; j < 4; ++j) hh.u[j] = f2h(acc[i][j]);
        *(ushort4*)&we16[(size_t)(p0 + ty * 4 + i) * C_ + c0 + tx * 4] = hh.v;
    }
}

// ---------------- 5. bsum[p] = bp[p] + sum_o wp[p][o]*bv[o] ----------------
__global__ __launch_bounds__(256) void bsum_kernel(
    const float* __restrict__ wp, const float* __restrict__ bv,
    const float* __restrict__ bp, float* __restrict__ bsum) {
    int p = blockIdx.x * 4 + (threadIdx.x >> 6);   // grid 128 -> p in [0,512)
    int lane = threadIdx.x & 63;
    const float* row = wp + (size_t)p * C_;
    f32x4 w0 = *(const f32x4*)&row[lane * 8];
    f32x4 w1 = *(const f32x4*)&row[lane * 8 + 4];
    f32x4 b0 = *(const f32x4*)&bv[lane * 8];
    f32x4 b1 = *(const f32x4*)&bv[lane * 8 + 4];
    float s = w0[0]*b0[0] + w0[1]*b0[1] + w0[2]*b0[2] + w0[3]*b0[3]
            + w1[0]*b1[0] + w1[1]*b1[1] + w1[2]*b1[2] + w1[3]*b1[3];
#pragma unroll
    for (int off = 32; off; off >>= 1) s += __shfl_down(s, off);
    if (lane == 0) bsum[p] = bp[p] + s;
}

// ---------------- 6. qkv GEMM (q, k, vp^T from h) ----------------
__global__ __launch_bounds__(256) void gemm_qkv(
    const ushort* __restrict__ h16,
    const ushort* __restrict__ wq16, const ushort* __restrict__ wk16,
    const ushort* __restrict__ we16,
    const float* __restrict__ bq, const float* __restrict__ bk,
    ushort* __restrict__ q16, ushort* __restrict__ k16,
    ushort* __restrict__ vpt16) {
    // XCD-chunked bijective swizzle (nwg=1536, %8==0)
    int D = blockIdx.x + 12 * blockIdx.y;
    int L = ((D & 7) * 192) + (D >> 3);
    int lx = L % 12, mt = L / 12;
    int wsel = lx >> 2, ct = lx & 3;

    const ushort* Bw = wsel == 0 ? wq16 : (wsel == 1 ? wk16 : we16);
    const float* bias = wsel == 0 ? bq : bk;

    f32x4 acc[4][4]; ACC_ZERO(acc);
    gemm_core_f16(h16 + (size_t)mt * 128 * C_, C_,
                  Bw + (size_t)ct * 128 * C_, C_, C_, acc);

    int tid = threadIdx.x, wave = tid >> 6, lane = tid & 63;
    int wm = wave >> 1, wn = wave & 1, lrow = lane & 15, lk = lane >> 4;

    if (wsel < 2) {
        ushort* oh = wsel ? k16 : q16;
        float scale = wsel ? 1.f : QSCALE_;
#pragma unroll
        for (int mf = 0; mf < 4; ++mf) {
            int gm = mt * 128 + wm * 64 + mf * 16 + 4 * lk;
#pragma unroll
            for (int nf = 0; nf < 4; ++nf) {
                int gc = ct * 128 + wn * 64 + nf * 16 + lrow;
                float bi = bias[gc];
#pragma unroll
                for (int rg = 0; rg < 4; ++rg)
                    oh[(size_t)(gm + rg) * C_ + gc] = f2h((acc[mf][nf][rg] + bi) * scale);
            }
        }
    } else {
        // vp^T [b][p][n]: 4 consecutive token-rows per reg-quad -> 8B stores
#pragma unroll
        for (int mf = 0; mf < 4; ++mf) {
            int gm0 = mt * 128 + wm * 64 + mf * 16 + 4 * lk;
            int b = gm0 >> 10, nl = gm0 & 1023;
#pragma unroll
            for (int nf = 0; nf < 4; ++nf) {
                int p = ct * 128 + wn * 64 + nf * 16 + lrow;
                union { ushort u[4]; ushort4 v; } hv;
#pragma unroll
                for (int rg = 0; rg < 4; ++rg) hv.u[rg] = f2h(acc[mf][nf][rg]);
                *(ushort4*)&vpt16[((size_t)b * C_ + p) * NTOK_ + nl] = hv.v;
            }
        }
    }
}

// ---------------- 7. scores = q @ k^T (per batch), fp32 out ----------------
__global__ __launch_bounds__(256) void gemm_scores(
    const ushort* __restrict__ q16, const ushort* __restrict__ k16,
    float* __restrict__ s) {
    // swizzle (nwg=1024)
    int D = blockIdx.x + (blockIdx.y << 3) + (blockIdx.z << 6);
    int L = ((D & 7) << 7) + (D >> 3);
    int nx = L & 7, my = (L >> 3) & 7, b = L >> 6;

    size_t ao = ((size_t)b * NTOK_ + my * 128) * C_;
    size_t bo = ((size_t)b * NTOK_ + nx * 128) * C_;
    f32x4 acc[4][4]; ACC_ZERO(acc);
    gemm_core_f16(q16 + ao, C_, k16 + bo, C_, C_, acc);

    int tid = threadIdx.x, wave = tid >> 6, lane = tid & 63;
    int wm = wave >> 1, wn = wave & 1, lrow = lane & 15, lk = lane >> 4;
#pragma unroll
    for (int mf = 0; mf < 4; ++mf) {
        int n = my * 128 + wm * 64 + mf * 16 + 4 * lk;
#pragma unroll
        for (int nf = 0; nf < 4; ++nf) {
            int m = nx * 128 + wn * 64 + nf * 16 + lrow;
#pragma unroll
            for (int rg = 0; rg < 4; ++rg)
                s[((size_t)b << 20) + (size_t)(n + rg) * NTOK_ + m] = acc[mf][nf][rg];
        }
    }
}

// ---------------- 8. softmax: fp32 row -> fp16 plane in place ----------------
__global__ __launch_bounds__(256) void softmax_kernel(float* __restrict__ s) {
    size_t row = blockIdx.x;
    float* p = s + (row << 10);
    int tid = threadIdx.x;
    f32x4 v = *(const f32x4*)&p[tid * 4];
    __shared__ float redm[4], reds[4];
    float m = fmaxf(fmaxf(v[0], v[1]), fmaxf(v[2], v[3]));
#pragma unroll
    for (int off = 32; off; off >>= 1) m = fmaxf(m, __shfl_down(m, off));
    int wid = tid >> 6, lane = tid & 63;
    if (lane == 0) redm[wid] = m;
    __syncthreads();
    m = fmaxf(fmaxf(redm[0], redm[1]), fmaxf(redm[2], redm[3]));
#pragma unroll
    for (int j = 0; j < 4; ++j) v[j] = __expf(v[j] - m);
    float sum = v[0] + v[1] + v[2] + v[3];
#pragma unroll
    for (int off = 32; off; off >>= 1) sum += __shfl_down(sum, off);
    if (lane == 0) reds[wid] = sum;
    __syncthreads();
    float inv = 1.f / (reds[0] + reds[1] + reds[2] + reds[3]);
    union { ushort u[4]; ushort4 w; } hh;
#pragma unroll
    for (int j = 0; j < 4; ++j) hh.u[j] = f2h(v[j] * inv);
    ushort* bp8 = (ushort*)p;  // row = 2048 ushorts; fp16 attn in [0,1024)
    *(ushort4*)&bp8[tid * 4] = hh.w;
}

// ---------------- 9. out = attn @ vp + bsum + x, NCHW ----------------
__global__ __launch_bounds__(256) void gemm_out(
    const float* __restrict__ s,
    const ushort* __restrict__ vpt16,
    const float* __restrict__ bsum, const float* __restrict__ x,
    float* __restrict__ out) {
    // swizzle (nwg=512)
    int D = blockIdx.x + (blockIdx.y << 2) + (blockIdx.z << 5);
    int L = ((D & 7) << 6) + (D >> 3);
    int ox = L & 3, ny = (L >> 2) & 7, b = L >> 5;

    const ushort* att = (const ushort*)s;
    const ushort* Ah = att + ((size_t)b * NTOK_ + ny * 128) * 2048;
    size_t bo = ((size_t)b * C_ + ox * 128) * NTOK_;
    f32x4 acc[4][4]; ACC_ZERO(acc);
    gemm_core_f16(Ah, 2048, vpt16 + bo, NTOK_, NTOK_, acc);

    int tid = threadIdx.x, wave = tid >> 6, lane = tid & 63;
    int wm = wave >> 1, wn = wave & 1, lrow = lane & 15, lk = lane >> 4;
#pragma unroll
    for (int mf = 0; mf < 4; ++mf) {
        int n0l = ny * 128 + wm * 64 + mf * 16 + 4 * lk;
#pragma unroll
        for (int nf = 0; nf < 4; ++nf) {
            int oc = ox * 128 + wn * 64 + nf * 16 + lrow;
            size_t base = ((size_t)b * C_ + oc) * NTOK_ + n0l;
            f32x4 xr = *(const f32x4*)&x[base];
            float bs = bsum[oc];
            f32x4 rv;
#pragma unroll
            for (int rg = 0; rg < 4; ++rg) rv[rg] = acc[mf][nf][rg] + bs + xr[rg];
            *(f32x4*)&out[base] = rv;
        }
    }
}

extern "C" void kernel_launch(void* const* d_in, const int* in_sizes, int n_in,
                              void* d_out, int out_size, void* d_ws, size_t ws_size,
                              hipStream_t stream) {
    const float* x  = (const float*)d_in[0];
    const float* gw = (const float*)d_in[1];
    const float* gb = (const float*)d_in[2];
    const float* wq = (const float*)d_in[3];
    const float* bq = (const float*)d_in[4];
    const float* wk = (const float*)d_in[5];
    const float* bk = (const float*)d_in[6];
    const float* wv = (const float*)d_in[7];
    const float* bv = (const float*)d_in[8];
    const float* wp = (const float*)d_in[9];
    const float* bp = (const float*)d_in[10];
    float* out = (float*)d_out;

    const size_t TOKC2 = (size_t)B_ * NTOK_ * C_ * 2;   // one fp16 plane (16 MB)
    const size_t W2 = (size_t)C_ * C_ * 2;               // 512 KB
    char* w = (char*)d_ws;
    auto carve = [&](size_t bytes) { char* p = w; w += (bytes + 255) & ~(size_t)255; return p; };

    float*  scale_a = (float*)carve(B_ * C_ * 4);
    float*  bias_a  = (float*)carve(B_ * C_ * 4);
    float*  bsumv   = (float*)carve(C_ * 4);
    ushort* h16     = (ushort*)carve(TOKC2);
    ushort* wq16    = (ushort*)carve(W2);
    ushort* wk16    = (ushort*)carve(W2);
    ushort* we16    = (ushort*)carve(W2);
    ushort* q16     = (ushort*)carve(TOKC2);
    ushort* k16     = (ushort*)carve(TOKC2);
    ushort* vpt16   = (ushort*)carve(TOKC2);
    float*  scores  = (float*)carve((size_t)B_ * NTOK_ * NTOK_ * 4);  // 64 MB
    if ((size_t)(w - (char*)d_ws) > ws_size) return;

    gn_stats_kernel<<<B_ * 32, 256, 0, stream>>>(x, gw, gb, scale_a, bias_a);
    prep_h_kernel<<<dim3(8, 16, B_), 256, 0, stream>>>(x, scale_a, bias_a, h16);
    prep_w_kernel<<<256, 256, 0, stream>>>(wq, wk, wq16, wk16);
    weff_kernel<<<dim3(8, 8), 256, 0, stream>>>(wp, wv, we16);
    bsum_kernel<<<128, 256, 0, stream>>>(wp, bv, bp, bsumv);
    gemm_qkv<<<dim3(12, 128), 256, 0, stream>>>(h16, wq16, wk16, we16, bq, bk,
                                                q16, k16, vpt16);
    gemm_scores<<<dim3(8, 8, B_), 256, 0, stream>>>(q16, k16, scores);
    softmax_kernel<<<B_ * NTOK_, 256, 0, stream>>>(scores);
    gemm_out<<<dim3(4, 8, B_), 256, 0, stream>>>(scores, vpt16, bsumv, x, out);
}

// Round 7
// 252.683 us; speedup vs baseline: 1.6787x; 1.0160x over previous
//
#include <hip/hip_runtime.h>
#include <hip/hip_bf16.h>

// AttnBlock: GroupNorm + single-head attention (N=1024 tokens, C=512) + residual.
// B=16. fp16 single-plane MFMA GEMMs (R6, passing at absmax 0.03125).
// R7 changes vs R6 (256.7 us):
//  - GEMM core: T3-minimum 2-phase pipeline. Double-buffered LDS (2x32KB);
//    next K-tile's global_load_lds issued BEFORE current tile's ds_read+MFMA;
//    ONE barrier per K-step (implicit vmcnt(0) drain lands after compute has
//    hidden the load latency). R6 was stage;barrier;compute;barrier = serial
//    global-latency drain every K-step (MfmaUtil 23%, occupancy 21%).
//  - gn_stats + prep_h fused into gn_prep (one 64MB read of x instead of two,
//    one launch fewer). Read/frag paths and all numerics identical to R6.

#define B_ 16
#define C_ 512
#define NTOK_ 1024
#define CPG_ 16
#define EPS_ 1e-5f
#define QSCALE_ 0.04419417382415922f  // 512^-0.5

typedef __attribute__((ext_vector_type(8))) _Float16 f16x8;  // 4 VGPR
typedef __attribute__((ext_vector_type(4))) float f32x4;
typedef const void __attribute__((address_space(1)))* gas1_t;
typedef void __attribute__((address_space(3)))* las3_t;

__device__ __forceinline__ ushort f2h(float x) {
    union { _Float16 h; ushort u; } c; c.h = (_Float16)x; return c.u;
}

// =================== fp16 MFMA GEMM core (2-phase pipelined) ===================
// C[128 x 128] += A · B^T (rows of B = output cols), fp16 (as ushort*), K%64==0.
// acc[m][n]: wave (wm,wn); C row = wm*64+m*16+4*lk+reg, col = wn*64+n*16+lrow.
// LDS per buffer: A rows [0,16K), B rows [16K,32K); row=128B; 16B chunk c of a
// row stored at slot c^(row&7) -> conflict-free ds_read_b128 (verified: R6
// SQ_LDS_BANK_CONFLICT == 0). Staged by global_load_lds w=16 with pre-swizzled
// per-lane source (sel=(lane&7)^(lane>>3) is the same involution).
__device__ __forceinline__ void gemm_core_f16(
    const ushort* __restrict__ A, int lda,
    const ushort* __restrict__ B, int ldb,
    int K, f32x4 acc[4][4])
{
    __shared__ alignas(16) char ldsc[2][32768];
    const int tid  = threadIdx.x;
    const int wave = tid >> 6, lane = tid & 63;
    const int wm = wave >> 1, wn = wave & 1;
    const int lrow = lane & 15, lk = lane >> 4;

    // staging roles: waves 0,1 -> A rows [0,64)/[64,128); waves 2,3 -> B same.
    const int isB = wave >> 1;
    const ushort* P = isB ? B : A;
    const int ld = isB ? ldb : lda;
    const int sel = (lane & 7) ^ (lane >> 3);
    const int rowbase = ((wave & 1) << 6) + (lane >> 3);
    const ushort* src0 = P + (size_t)rowbase * ld + sel * 8;
    const int dstoff = (isB << 14) + ((wave & 1) << 13);

    const int nsteps = K >> 6;

    // prologue: stage tile 0 into buffer 0
#pragma unroll
    for (int j = 0; j < 8; ++j) {
        __builtin_amdgcn_global_load_lds(
            (gas1_t)(src0 + (size_t)(j << 3) * ld),
            (las3_t)(&ldsc[0][0] + dstoff + (j << 10)), 16, 0, 0);
    }
    __syncthreads();  // vmcnt(0): tile 0 resident

    for (int t = 0; t < nsteps; ++t) {
        const char* cur = &ldsc[t & 1][0];
        // issue next tile's stage FIRST: global latency hides under ds_read+MFMA
        if (t + 1 < nsteps) {
            const ushort* st = src0 + (t + 1) * 64;
            char* nxt = &ldsc[(t + 1) & 1][0] + dstoff;
#pragma unroll
            for (int j = 0; j < 8; ++j) {
                __builtin_amdgcn_global_load_lds(
                    (gas1_t)(st + (size_t)(j << 3) * ld),
                    (las3_t)(nxt + (j << 10)), 16, 0, 0);
            }
        }

        f16x8 af[4][2], bf[4][2];
#pragma unroll
        for (int m = 0; m < 4; ++m) {
            int row = wm * 64 + m * 16 + lrow;
            const char* base = cur + row * 128;
#pragma unroll
            for (int ks = 0; ks < 2; ++ks) {
                int c = ks * 4 + lk;
                af[m][ks] = *(const f16x8*)(base + ((c ^ (row & 7)) << 4));
            }
        }
#pragma unroll
        for (int n = 0; n < 4; ++n) {
            int row = wn * 64 + n * 16 + lrow;
            const char* base = cur + 16384 + row * 128;
#pragma unroll
            for (int ks = 0; ks < 2; ++ks) {
                int c = ks * 4 + lk;
                bf[n][ks] = *(const f16x8*)(base + ((c ^ (row & 7)) << 4));
            }
        }
#pragma unroll
        for (int m = 0; m < 4; ++m)
#pragma unroll
            for (int n = 0; n < 4; ++n) {
                acc[m][n] = __builtin_amdgcn_mfma_f32_16x16x32_f16(af[m][0], bf[n][0], acc[m][n], 0, 0, 0);
                acc[m][n] = __builtin_amdgcn_mfma_f32_16x16x32_f16(af[m][1], bf[n][1], acc[m][n], 0, 0, 0);
            }
        // one barrier/K-step: drains stage(t+1) vmcnt + all waves' reads of cur
        __syncthreads();
    }
}

#define ACC_ZERO(acc) do { \
    _Pragma("unroll") for (int m_ = 0; m_ < 4; ++m_) \
    _Pragma("unroll") for (int n_ = 0; n_ < 4; ++n_) \
        acc[m_][n_] = (f32x4){0.f, 0.f, 0.f, 0.f}; \
} while (0)

// ---------------- 1. GroupNorm + affine + transpose -> h fp16 [b][n][c] ----------------
// One block per (b, group): 16 channels x 1024 px in LDS; stats in-block;
// writes h16 = (x - mu) * rstd * gw + gb, transposed, f16.
__global__ __launch_bounds__(256) void gn_prep_kernel(
    const float* __restrict__ x, const float* __restrict__ gw,
    const float* __restrict__ gb, ushort* __restrict__ h16) {
    __shared__ float sx[16][1028];   // +4 pad: c-walk dodges bank repeats
    __shared__ float red[8];
    __shared__ float smu, srstd;
    __shared__ float s_sc[16], s_bi[16];
    int bg = blockIdx.x;
    int b = bg >> 5, g = bg & 31;
    const float* xp = x + ((size_t)(b * C_ + g * CPG_) << 10);
    int tid = threadIdx.x;
    float s = 0.f, ss = 0.f;
    for (int i = tid; i < 4096; i += 256) {   // 16 ch * 256 f32x4
        int c = i >> 8, n4 = (i & 255) << 2;
        f32x4 v = *(const f32x4*)&xp[((size_t)c << 10) + n4];
        *(f32x4*)&sx[c][n4] = v;
        s += v[0] + v[1] + v[2] + v[3];
        ss += v[0]*v[0] + v[1]*v[1] + v[2]*v[2] + v[3]*v[3];
    }
#pragma unroll
    for (int off = 32; off; off >>= 1) {
        s += __shfl_down(s, off);
        ss += __shfl_down(ss, off);
    }
    int wid = tid >> 6, lane = tid & 63;
    if (lane == 0) { red[wid] = s; red[wid + 4] = ss; }
    __syncthreads();
    if (tid == 0) {
        float S = red[0] + red[1] + red[2] + red[3];
        float SS = red[4] + red[5] + red[6] + red[7];
        float mu = S * (1.f / 16384.f);
        float var = SS * (1.f / 16384.f) - mu * mu;
        smu = mu;
        srstd = rsqrtf(var + EPS_);
    }
    __syncthreads();
    if (tid < CPG_) {
        int c = g * CPG_ + tid;
        float sc = srstd * gw[c];
        s_sc[tid] = sc;
        s_bi[tid] = gb[c] - smu * sc;
    }
    __syncthreads();
    // write: thread owns 4 consecutive n; per n, 16 channels -> 2 uint4
#pragma unroll
    for (int jn = 0; jn < 4; ++jn) {
        int n = (tid << 2) + jn;
        union { ushort u[16]; uint4 v[2]; } pk;
#pragma unroll
        for (int c = 0; c < 16; ++c)
            pk.u[c] = f2h(sx[c][n] * s_sc[c] + s_bi[c]);
        size_t ob = (((size_t)b << 10) + n) * C_ + g * CPG_;
        *(uint4*)&h16[ob] = pk.v[0];
        *(uint4*)&h16[ob + 8] = pk.v[1];
    }
}

// ---------------- 3. prep_w: wq, wk -> fp16 ----------------
__global__ __launch_bounds__(256) void prep_w_kernel(
    const float* __restrict__ wq, const float* __restrict__ wk,
    ushort* __restrict__ wq16, ushort* __restrict__ wk16) {
    int i = blockIdx.x * 256 + threadIdx.x;  // one float4 of each matrix
    union { ushort u[4]; ushort4 v; } h;
    f32x4 a = ((const f32x4*)wq)[i];
#pragma unroll
    for (int j = 0; j < 4; ++j) h.u[j] = f2h(a[j]);
    ((ushort4*)wq16)[i] = h.v;
    f32x4 b = ((const f32x4*)wk)[i];
#pragma unroll
    for (int j = 0; j < 4; ++j) h.u[j] = f2h(b[j]);
    ((ushort4*)wk16)[i] = h.v;
}

// ---------------- 4. Weff = wp @ wv (fp32 VALU) -> fp16 ----------------
__global__ __launch_bounds__(256) void weff_kernel(
    const float* __restrict__ wp, const float* __restrict__ wv,
    ushort* __restrict__ we16) {
    __shared__ float As[16][68], Bs[16][68];
    int tid = threadIdx.x, ty = tid >> 4, tx = tid & 15;
    int c0 = blockIdx.x << 6, p0 = blockIdx.y << 6;
    int a_row = tid >> 2, a_kq = tid & 3;
    int b_m = tid >> 4, b_cq = tid & 15;
    float acc[4][4] = {};
    for (int k0 = 0; k0 < C_; k0 += 16) {
        f32x4 a4 = *(const f32x4*)&wp[(size_t)(p0 + a_row) * C_ + k0 + a_kq * 4];
        As[a_kq * 4 + 0][a_row] = a4[0]; As[a_kq * 4 + 1][a_row] = a4[1];
        As[a_kq * 4 + 2][a_row] = a4[2]; As[a_kq * 4 + 3][a_row] = a4[3];
        *(f32x4*)&Bs[b_m][b_cq * 4] =
            *(const f32x4*)&wv[(size_t)(k0 + b_m) * C_ + c0 + b_cq * 4];
        __syncthreads();
#pragma unroll
        for (int kk = 0; kk < 16; ++kk) {
            f32x4 av = *(const f32x4*)&As[kk][ty << 2];
            f32x4 bv = *(const f32x4*)&Bs[kk][tx << 2];
#pragma unroll
            for (int i = 0; i < 4; ++i)
#pragma unroll
                for (int j = 0; j < 4; ++j) acc[i][j] += av[i] * bv[j];
        }
        __syncthreads();
    }
#pragma unroll
    for (int i = 0; i < 4; ++i) {
        union { ushort u[4]; ushort4 v; } hh;
#pragma unroll
        for (int j = 0; j < 4; ++j) hh.u[j] = f2h(acc[i][j]);
        *(ushort4*)&we16[(size_t)(p0 + ty * 4 + i) * C_ + c0 + tx * 4] = hh.v;
    }
}

// ---------------- 5. bsum[p] = bp[p] + sum_o wp[p][o]*bv[o] ----------------
__global__ __launch_bounds__(256) void bsum_kernel(
    const float* __restrict__ wp, const float* __restrict__ bv,
    const float* __restrict__ bp, float* __restrict__ bsum) {
    int p = blockIdx.x * 4 + (threadIdx.x >> 6);   // grid 128 -> p in [0,512)
    int lane = threadIdx.x & 63;
    const float* row = wp + (size_t)p * C_;
    f32x4 w0 = *(const f32x4*)&row[lane * 8];
    f32x4 w1 = *(const f32x4*)&row[lane * 8 + 4];
    f32x4 b0 = *(const f32x4*)&bv[lane * 8];
    f32x4 b1 = *(const f32x4*)&bv[lane * 8 + 4];
    float s = w0[0]*b0[0] + w0[1]*b0[1] + w0[2]*b0[2] + w0[3]*b0[3]
            + w1[0]*b1[0] + w1[1]*b1[1] + w1[2]*b1[2] + w1[3]*b1[3];
#pragma unroll
    for (int off = 32; off; off >>= 1) s += __shfl_down(s, off);
    if (lane == 0) bsum[p] = bp[p] + s;
}

// ---------------- 6. qkv GEMM (q, k, vp^T from h) ----------------
__global__ __launch_bounds__(256) void gemm_qkv(
    const ushort* __restrict__ h16,
    const ushort* __restrict__ wq16, const ushort* __restrict__ wk16,
    const ushort* __restrict__ we16,
    const float* __restrict__ bq, const float* __restrict__ bk,
    ushort* __restrict__ q16, ushort* __restrict__ k16,
    ushort* __restrict__ vpt16) {
    // XCD-chunked bijective swizzle (nwg=1536, %8==0)
    int D = blockIdx.x + 12 * blockIdx.y;
    int L = ((D & 7) * 192) + (D >> 3);
    int lx = L % 12, mt = L / 12;
    int wsel = lx >> 2, ct = lx & 3;

    const ushort* Bw = wsel == 0 ? wq16 : (wsel == 1 ? wk16 : we16);
    const float* bias = wsel == 0 ? bq : bk;

    f32x4 acc[4][4]; ACC_ZERO(acc);
    gemm_core_f16(h16 + (size_t)mt * 128 * C_, C_,
                  Bw + (size_t)ct * 128 * C_, C_, C_, acc);

    int tid = threadIdx.x, wave = tid >> 6, lane = tid & 63;
    int wm = wave >> 1, wn = wave & 1, lrow = lane & 15, lk = lane >> 4;

    if (wsel < 2) {
        ushort* oh = wsel ? k16 : q16;
        float scale = wsel ? 1.f : QSCALE_;
#pragma unroll
        for (int mf = 0; mf < 4; ++mf) {
            int gm = mt * 128 + wm * 64 + mf * 16 + 4 * lk;
#pragma unroll
            for (int nf = 0; nf < 4; ++nf) {
                int gc = ct * 128 + wn * 64 + nf * 16 + lrow;
                float bi = bias[gc];
#pragma unroll
                for (int rg = 0; rg < 4; ++rg)
                    oh[(size_t)(gm + rg) * C_ + gc] = f2h((acc[mf][nf][rg] + bi) * scale);
            }
        }
    } else {
        // vp^T [b][p][n]: 4 consecutive token-rows per reg-quad -> 8B stores
#pragma unroll
        for (int mf = 0; mf < 4; ++mf) {
            int gm0 = mt * 128 + wm * 64 + mf * 16 + 4 * lk;
            int b = gm0 >> 10, nl = gm0 & 1023;
#pragma unroll
            for (int nf = 0; nf < 4; ++nf) {
                int p = ct * 128 + wn * 64 + nf * 16 + lrow;
                union { ushort u[4]; ushort4 v; } hv;
#pragma unroll
                for (int rg = 0; rg < 4; ++rg) hv.u[rg] = f2h(acc[mf][nf][rg]);
                *(ushort4*)&vpt16[((size_t)b * C_ + p) * NTOK_ + nl] = hv.v;
            }
        }
    }
}

// ---------------- 7. scores = q @ k^T (per batch), fp32 out ----------------
__global__ __launch_bounds__(256) void gemm_scores(
    const ushort* __restrict__ q16, const ushort* __restrict__ k16,
    float* __restrict__ s) {
    // swizzle (nwg=1024)
    int D = blockIdx.x + (blockIdx.y << 3) + (blockIdx.z << 6);
    int L = ((D & 7) << 7) + (D >> 3);
    int nx = L & 7, my = (L >> 3) & 7, b = L >> 6;

    size_t ao = ((size_t)b * NTOK_ + my * 128) * C_;
    size_t bo = ((size_t)b * NTOK_ + nx * 128) * C_;
    f32x4 acc[4][4]; ACC_ZERO(acc);
    gemm_core_f16(q16 + ao, C_, k16 + bo, C_, C_, acc);

    int tid = threadIdx.x, wave = tid >> 6, lane = tid & 63;
    int wm = wave >> 1, wn = wave & 1, lrow = lane & 15, lk = lane >> 4;
#pragma unroll
    for (int mf = 0; mf < 4; ++mf) {
        int n = my * 128 + wm * 64 + mf * 16 + 4 * lk;
#pragma unroll
        for (int nf = 0; nf < 4; ++nf) {
            int m = nx * 128 + wn * 64 + nf * 16 + lrow;
#pragma unroll
            for (int rg = 0; rg < 4; ++rg)
                s[((size_t)b << 20) + (size_t)(n + rg) * NTOK_ + m] = acc[mf][nf][rg];
        }
    }
}

// ---------------- 8. softmax: fp32 row -> fp16 plane in place ----------------
__global__ __launch_bounds__(256) void softmax_kernel(float* __restrict__ s) {
    size_t row = blockIdx.x;
    float* p = s + (row << 10);
    int tid = threadIdx.x;
    f32x4 v = *(const f32x4*)&p[tid * 4];
    __shared__ float redm[4], reds[4];
    float m = fmaxf(fmaxf(v[0], v[1]), fmaxf(v[2], v[3]));
#pragma unroll
    for (int off = 32; off; off >>= 1) m = fmaxf(m, __shfl_down(m, off));
    int wid = tid >> 6, lane = tid & 63;
    if (lane == 0) redm[wid] = m;
    __syncthreads();
    m = fmaxf(fmaxf(redm[0], redm[1]), fmaxf(redm[2], redm[3]));
#pragma unroll
    for (int j = 0; j < 4; ++j) v[j] = __expf(v[j] - m);
    float sum = v[0] + v[1] + v[2] + v[3];
#pragma unroll
    for (int off = 32; off; off >>= 1) sum += __shfl_down(sum, off);
    if (lane == 0) reds[wid] = sum;
    __syncthreads();
    float inv = 1.f / (reds[0] + reds[1] + reds[2] + reds[3]);
    union { ushort u[4]; ushort4 w; } hh;
#pragma unroll
    for (int j = 0; j < 4; ++j) hh.u[j] = f2h(v[j] * inv);
    ushort* bp8 = (ushort*)p;  // row = 2048 ushorts; fp16 attn in [0,1024)
    *(ushort4*)&bp8[tid * 4] = hh.w;
}

// ---------------- 9. out = attn @ vp + bsum + x, NCHW ----------------
__global__ __launch_bounds__(256) void gemm_out(
    const float* __restrict__ s,
    const ushort* __restrict__ vpt16,
    const float* __restrict__ bsum, const float* __restrict__ x,
    float* __restrict__ out) {
    // swizzle (nwg=512)
    int D = blockIdx.x + (blockIdx.y << 2) + (blockIdx.z << 5);
    int L = ((D & 7) << 6) + (D >> 3);
    int ox = L & 3, ny = (L >> 2) & 7, b = L >> 5;

    const ushort* att = (const ushort*)s;
    const ushort* Ah = att + ((size_t)b * NTOK_ + ny * 128) * 2048;
    size_t bo = ((size_t)b * C_ + ox * 128) * NTOK_;
    f32x4 acc[4][4]; ACC_ZERO(acc);
    gemm_core_f16(Ah, 2048, vpt16 + bo, NTOK_, NTOK_, acc);

    int tid = threadIdx.x, wave = tid >> 6, lane = tid & 63;
    int wm = wave >> 1, wn = wave & 1, lrow = lane & 15, lk = lane >> 4;
#pragma unroll
    for (int mf = 0; mf < 4; ++mf) {
        int n0l = ny * 128 + wm * 64 + mf * 16 + 4 * lk;
#pragma unroll
        for (int nf = 0; nf < 4; ++nf) {
            int oc = ox * 128 + wn * 64 + nf * 16 + lrow;
            size_t base = ((size_t)b * C_ + oc) * NTOK_ + n0l;
            f32x4 xr = *(const f32x4*)&x[base];
            float bs = bsum[oc];
            f32x4 rv;
#pragma unroll
            for (int rg = 0; rg < 4; ++rg) rv[rg] = acc[mf][nf][rg] + bs + xr[rg];
            *(f32x4*)&out[base] = rv;
        }
    }
}

extern "C" void kernel_launch(void* const* d_in, const int* in_sizes, int n_in,
                              void* d_out, int out_size, void* d_ws, size_t ws_size,
                              hipStream_t stream) {
    const float* x  = (const float*)d_in[0];
    const float* gw = (const float*)d_in[1];
    const float* gb = (const float*)d_in[2];
    const float* wq = (const float*)d_in[3];
    const float* bq = (const float*)d_in[4];
    const float* wk = (const float*)d_in[5];
    const float* bk = (const float*)d_in[6];
    const float* wv = (const float*)d_in[7];
    const float* bv = (const float*)d_in[8];
    const float* wp = (const float*)d_in[9];
    const float* bp = (const float*)d_in[10];
    float* out = (float*)d_out;

    const size_t TOKC2 = (size_t)B_ * NTOK_ * C_ * 2;   // one fp16 plane (16 MB)
    const size_t W2 = (size_t)C_ * C_ * 2;               // 512 KB
    char* w = (char*)d_ws;
    auto carve = [&](size_t bytes) { char* p = w; w += (bytes + 255) & ~(size_t)255; return p; };

    float*  bsumv   = (float*)carve(C_ * 4);
    ushort* h16     = (ushort*)carve(TOKC2);
    ushort* wq16    = (ushort*)carve(W2);
    ushort* wk16    = (ushort*)carve(W2);
    ushort* we16    = (ushort*)carve(W2);
    ushort* q16     = (ushort*)carve(TOKC2);
    ushort* k16     = (ushort*)carve(TOKC2);
    ushort* vpt16   = (ushort*)carve(TOKC2);
    float*  scores  = (float*)carve((size_t)B_ * NTOK_ * NTOK_ * 4);  // 64 MB
    if ((size_t)(w - (char*)d_ws) > ws_size) return;

    gn_prep_kernel<<<B_ * 32, 256, 0, stream>>>(x, gw, gb, h16);
    prep_w_kernel<<<256, 256, 0, stream>>>(wq, wk, wq16, wk16);
    weff_kernel<<<dim3(8, 8), 256, 0, stream>>>(wp, wv, we16);
    bsum_kernel<<<128, 256, 0, stream>>>(wp, bv, bp, bsumv);
    gemm_qkv<<<dim3(12, 128), 256, 0, stream>>>(h16, wq16, wk16, we16, bq, bk,
                                                q16, k16, vpt16);
    gemm_scores<<<dim3(8, 8, B_), 256, 0, stream>>>(q16, k16, scores);
    softmax_kernel<<<B_ * NTOK_, 256, 0, stream>>>(scores);
    gemm_out<<<dim3(4, 8, B_), 256, 0, stream>>>(scores, vpt16, bsumv, x, out);
}